// Round 6
// baseline (879.121 us; speedup 1.0000x reference)
//
#include <hip/hip_runtime.h>

#define DD 64
#define NPW 4   // nodes per wave
#define WPB 4   // waves per block (256 threads)

static __device__ __forceinline__ int rfl(int x) {
    return __builtin_amdgcn_readfirstlane(x);
}

// ---- degree over src (float, for dis) + count over dst (int, for CSR) ----
__global__ void degcnt_kernel(const int* __restrict__ src, const int* __restrict__ dst,
                              float* __restrict__ deg, int* __restrict__ cnt, int E) {
    int e = blockIdx.x * blockDim.x + threadIdx.x;
    if (e < E) {
        atomicAdd(&deg[src[e]], 1.0f);
        atomicAdd(&cnt[dst[e]], 1);
    }
}

// ---- dis = deg>0 ? rsqrt(deg) : 0 (in place) ----
__global__ void dis_kernel(float* __restrict__ deg, int N) {
    int n = blockIdx.x * blockDim.x + threadIdx.x;
    if (n < N) {
        float d = deg[n];
        deg[n] = (d > 0.0f) ? rsqrtf(d) : 0.0f;
    }
}

// ---- scan step 1: per-block (1024) exclusive scan of cnt -> rowptr; block sums -> bsum ----
__global__ __launch_bounds__(1024) void scan1_kernel(const int* __restrict__ cnt,
                                                     int* __restrict__ rowptr,
                                                     int* __restrict__ bsum, int N) {
    __shared__ int tmp[1024];
    int t = threadIdx.x;
    int g = blockIdx.x * 1024 + t;
    int v = (g < N) ? cnt[g] : 0;
    tmp[t] = v;
    __syncthreads();
    for (int off = 1; off < 1024; off <<= 1) {
        int a = (t >= off) ? tmp[t - off] : 0;
        __syncthreads();
        tmp[t] += a;
        __syncthreads();
    }
    if (g < N) rowptr[g] = tmp[t] - v;   // exclusive within block
    if (t == 1023) bsum[blockIdx.x] = tmp[1023];
}

// ---- scan step 2: one block, exclusive scan of bsum (nb <= 128) in place ----
__global__ __launch_bounds__(128) void scan2_kernel(int* __restrict__ data, int n) {
    __shared__ int tmp[128];
    int t = threadIdx.x;
    int v = (t < n) ? data[t] : 0;
    tmp[t] = v;
    __syncthreads();
    for (int off = 1; off < 128; off <<= 1) {
        int a = (t >= off) ? tmp[t - off] : 0;
        __syncthreads();
        tmp[t] += a;
        __syncthreads();
    }
    if (t < n) data[t] = tmp[t] - v;
}

// ---- scan step 3: add block offsets; set rowptr[N]=E ----
__global__ void scan3_kernel(int* __restrict__ rowptr, const int* __restrict__ bsum,
                             int N, int E) {
    int g = blockIdx.x * blockDim.x + threadIdx.x;
    if (g < N) rowptr[g] += bsum[g >> 10];
    if (g == 0) rowptr[N] = E;
}

// ---- CSR fill: adj[pos] = (src, -dis[src]*dis[dst]) packed ----
__global__ void fill_kernel(const int* __restrict__ src, const int* __restrict__ dst,
                            const float* __restrict__ dis, const int* __restrict__ rowptr,
                            int* __restrict__ fillc, int2* __restrict__ adj, int E) {
    int e = blockIdx.x * blockDim.x + threadIdx.x;
    if (e < E) {
        int s = src[e], d = dst[e];
        int pos = rowptr[d] + atomicAdd(&fillc[d], 1);
        adj[pos] = make_int2(s, __float_as_int(-dis[s] * dis[d]));
    }
}

// ---- gemm0: out = b + x @ W0 (batched 4 nodes/wave, W0 in LDS) ----
__global__ __launch_bounds__(256, 8) void gemm0_kernel(
        const float* __restrict__ x, const float* __restrict__ W0,
        const float* __restrict__ bias, float* __restrict__ out, int N) {
    __shared__ float Ws[DD * DD];
    int t = threadIdx.x;
    {
        const float4* s4 = reinterpret_cast<const float4*>(W0);
        float4* d4 = reinterpret_cast<float4*>(Ws);
        #pragma unroll
        for (int i = 0; i < 4; ++i) d4[t + 256 * i] = s4[t + 256 * i];
    }
    __syncthreads();
    int nl = t >> 6, lane = t & 63;
    int node0 = (blockIdx.x * WPB + nl) * NPW;
    if (node0 >= N) return;
    int nv = min(NPW, N - node0);

    float bsv = bias[lane];
    float v[NPW], o[NPW];
    #pragma unroll
    for (int ni = 0; ni < NPW; ++ni) {
        v[ni] = (ni < nv) ? x[(long long)(node0 + ni) * DD + lane] : 0.f;
        o[ni] = bsv;
    }
    #pragma unroll 4
    for (int jj = 0; jj < DD; ++jj) {
        float w = Ws[jj * DD + lane];
        #pragma unroll
        for (int ni = 0; ni < NPW; ++ni) o[ni] += __shfl(v[ni], jj, 64) * w;
    }
    #pragma unroll
    for (int ni = 0; ni < NPW; ++ni)
        if (ni < nv) out[(long long)(node0 + ni) * DD + lane] = o[ni];
}

// ---- prop: Txk = scale*gather(h) - tx0 ; txout = Txk (optional) ; out += Txk@Wk ----
// Column-split gather: lane = column, edge loop wave-uniform (SGPR broadcast of
// (src,w)), one coalesced 256B row load + 1 FMA per edge, no shuffle reduce.
// NOTE: txout may alias tx0 (own-index read-before-write) — no __restrict__ there.
__global__ __launch_bounds__(256, 8) void prop_kernel(
        const int* __restrict__ rowptr, const int2* __restrict__ adj,
        const float* __restrict__ h, const float* tx0,
        const float* __restrict__ Wk,
        float* txout, float* __restrict__ out,
        float scale, int N) {
    __shared__ float Ws[DD * DD];
    int t = threadIdx.x;
    {
        const float4* s4 = reinterpret_cast<const float4*>(Wk);
        float4* d4 = reinterpret_cast<float4*>(Ws);
        #pragma unroll
        for (int i = 0; i < 4; ++i) d4[t + 256 * i] = s4[t + 256 * i];
    }
    __syncthreads();

    int nl = t >> 6, lane = t & 63;
    int node0 = (blockIdx.x * WPB + nl) * NPW;
    if (node0 >= N) return;
    int nv = min(NPW, N - node0);

    float v[NPW], o[NPW];
    #pragma unroll
    for (int ni = 0; ni < NPW; ++ni) { v[ni] = 0.f; o[ni] = 0.f; }

    const float* hp = h + lane;
    for (int ni = 0; ni < nv; ++ni) {
        int node = node0 + ni;
        int beg = rfl(rowptr[node]);
        int end = rfl(rowptr[node + 1]);
        float acc = 0.f;
        int j = beg;
        for (; j + 3 < end; j += 4) {
            int2 e0 = adj[j], e1 = adj[j + 1], e2 = adj[j + 2], e3 = adj[j + 3];
            int s0 = rfl(e0.x); float w0 = __int_as_float(rfl(e0.y));
            int s1 = rfl(e1.x); float w1 = __int_as_float(rfl(e1.y));
            int s2 = rfl(e2.x); float w2 = __int_as_float(rfl(e2.y));
            int s3 = rfl(e3.x); float w3 = __int_as_float(rfl(e3.y));
            float g0 = hp[(long long)s0 * DD];
            float g1 = hp[(long long)s1 * DD];
            float g2 = hp[(long long)s2 * DD];
            float g3 = hp[(long long)s3 * DD];
            acc += w0 * g0;
            acc += w1 * g1;
            acc += w2 * g2;
            acc += w3 * g3;
        }
        for (; j < end; ++j) {
            int2 e = adj[j];
            int s = rfl(e.x); float w = __int_as_float(rfl(e.y));
            acc += w * hp[(long long)s * DD];
        }
        long long base = (long long)node * DD;
        float t0v = tx0 ? tx0[base + lane] : 0.f;
        float val = scale * acc - t0v;
        if (txout) txout[base + lane] = val;
        v[ni] = val;
    }

    #pragma unroll
    for (int ni = 0; ni < NPW; ++ni)
        if (ni < nv) o[ni] = out[(long long)(node0 + ni) * DD + lane];

    #pragma unroll 4
    for (int jj = 0; jj < DD; ++jj) {
        float w = Ws[jj * DD + lane];
        #pragma unroll
        for (int ni = 0; ni < NPW; ++ni) o[ni] += __shfl(v[ni], jj, 64) * w;
    }

    #pragma unroll
    for (int ni = 0; ni < NPW; ++ni)
        if (ni < nv) out[(long long)(node0 + ni) * DD + lane] = o[ni];
}

extern "C" void kernel_launch(void* const* d_in, const int* in_sizes, int n_in,
                              void* d_out, int out_size, void* d_ws, size_t ws_size,
                              hipStream_t stream) {
    const float* x  = (const float*)d_in[0];
    const int*   ei = (const int*)d_in[1];
    const float* W  = (const float*)d_in[2];
    const float* b  = (const float*)d_in[3];
    float* out = (float*)d_out;

    const int N = in_sizes[0] / DD;
    const int E = in_sizes[1] / 2;
    const int K = in_sizes[2] / (DD * DD);
    const long long ND = (long long)N * DD;

    const int* src = ei;
    const int* dst = ei + E;

    float* ws    = (float*)d_ws;
    float* dis   = ws;                          // N floats
    int*   cnt   = (int*)(dis + N);             // N
    int*   fillc = cnt + N;                     // N
    int*   rowptr= fillc + N;                   // N+1
    int*   bsum  = rowptr + N + 1;              // 128
    int2*  adj   = (int2*)(bsum + 128);         // E (8B each, 8B-aligned)
    float* B1    = (float*)(adj + E);           // ND
    float* B2    = B1 + ND;                     // ND

    // zero dis, cnt, fillc in one memset (contiguous)
    hipMemsetAsync(dis, 0, (size_t)(3 * N) * sizeof(float), stream);

    degcnt_kernel<<<(E + 255) / 256, 256, 0, stream>>>(src, dst, dis, cnt, E);
    dis_kernel<<<(N + 255) / 256, 256, 0, stream>>>(dis, N);

    const int nb = (N + 1023) / 1024;           // <= 128 required
    scan1_kernel<<<nb, 1024, 0, stream>>>(cnt, rowptr, bsum, N);
    scan2_kernel<<<1, 128, 0, stream>>>(bsum, nb);
    scan3_kernel<<<(N + 255) / 256, 256, 0, stream>>>(rowptr, bsum, N, E);
    fill_kernel<<<(E + 255) / 256, 256, 0, stream>>>(src, dst, dis, rowptr, fillc,
                                                     adj, E);

    const int pgrid = (N + WPB * NPW - 1) / (WPB * NPW);

    // out = b + x @ W0
    gemm0_kernel<<<pgrid, 256, 0, stream>>>(x, W, b, out, N);

    // k=1: Tx1 = prop(x) -> B1 ; out += Tx1 @ W1
    prop_kernel<<<pgrid, 256, 0, stream>>>(rowptr, adj, x, nullptr,
                                           W + DD * DD, B1, out, 1.0f, N);

    // k>=2: Txk = 2*prop(Tx1) - Tx0 ; out += Txk@Wk
    // Rotation invariant: target always aliases the NEXT tx0 (safe: tx0 is
    // read only at the owning thread's index before the write); never aliases h.
    const float* t0 = x;
    float* t1 = B1;
    float* tg = B2;
    for (int k = 2; k < K; ++k) {
        float* txw = (k == K - 1) ? nullptr : tg;   // last Tx is never read
        prop_kernel<<<pgrid, 256, 0, stream>>>(rowptr, adj, t1, t0,
                                               W + (long long)k * DD * DD,
                                               txw, out, 2.0f, N);
        const float* nt0 = t1;   // Tx_{k-1}
        float* nt1 = tg;         // Tx_k
        tg = (float*)nt0;        // next target aliases next tx0
        t0 = nt0;
        t1 = nt1;
    }
}

// Round 8
// 854.838 us; speedup vs baseline: 1.0284x; 1.0284x over previous
//
#include <hip/hip_runtime.h>

#define DD 64
#define NPW 4   // nodes per wave
#define WPB 4   // waves per block (256 threads)

typedef int vint4 __attribute__((ext_vector_type(4)));

static __device__ __forceinline__ int rfl(int x) {
    return __builtin_amdgcn_readfirstlane(x);
}

// ---- degree over src (float, for dis) + count over dst (int, for CSR) ----
// 4 edges/thread, nontemporal edge reads (keep L2 for the counter lines).
__global__ void degcnt_kernel(const int* __restrict__ src, const int* __restrict__ dst,
                              float* __restrict__ deg, int* __restrict__ cnt, int E) {
    int i = blockIdx.x * blockDim.x + threadIdx.x;
    int e0 = i * 4;
    if (e0 + 3 < E) {
        vint4 s = __builtin_nontemporal_load(reinterpret_cast<const vint4*>(src + e0));
        vint4 d = __builtin_nontemporal_load(reinterpret_cast<const vint4*>(dst + e0));
        atomicAdd(&deg[s.x], 1.0f); atomicAdd(&deg[s.y], 1.0f);
        atomicAdd(&deg[s.z], 1.0f); atomicAdd(&deg[s.w], 1.0f);
        atomicAdd(&cnt[d.x], 1); atomicAdd(&cnt[d.y], 1);
        atomicAdd(&cnt[d.z], 1); atomicAdd(&cnt[d.w], 1);
    } else {
        for (int e = e0; e < E; ++e) {
            atomicAdd(&deg[src[e]], 1.0f);
            atomicAdd(&cnt[dst[e]], 1);
        }
    }
}

// ---- dis = deg>0 ? rsqrt(deg) : 0 (in place) ----
__global__ void dis_kernel(float* __restrict__ deg, int N) {
    int n = blockIdx.x * blockDim.x + threadIdx.x;
    if (n < N) {
        float d = deg[n];
        deg[n] = (d > 0.0f) ? rsqrtf(d) : 0.0f;
    }
}

// ---- scan step 1: per-block (1024) exclusive scan of cnt -> rowptr; block sums -> bsum ----
__global__ __launch_bounds__(1024) void scan1_kernel(const int* __restrict__ cnt,
                                                     int* __restrict__ rowptr,
                                                     int* __restrict__ bsum, int N) {
    __shared__ int tmp[1024];
    int t = threadIdx.x;
    int g = blockIdx.x * 1024 + t;
    int v = (g < N) ? cnt[g] : 0;
    tmp[t] = v;
    __syncthreads();
    for (int off = 1; off < 1024; off <<= 1) {
        int a = (t >= off) ? tmp[t - off] : 0;
        __syncthreads();
        tmp[t] += a;
        __syncthreads();
    }
    if (g < N) rowptr[g] = tmp[t] - v;   // exclusive within block
    if (t == 1023) bsum[blockIdx.x] = tmp[1023];
}

// ---- scan step 2: one block, exclusive scan of bsum (nb <= 128) in place ----
__global__ __launch_bounds__(128) void scan2_kernel(int* __restrict__ data, int n) {
    __shared__ int tmp[128];
    int t = threadIdx.x;
    int v = (t < n) ? data[t] : 0;
    tmp[t] = v;
    __syncthreads();
    for (int off = 1; off < 128; off <<= 1) {
        int a = (t >= off) ? tmp[t - off] : 0;
        __syncthreads();
        tmp[t] += a;
        __syncthreads();
    }
    if (t < n) data[t] = tmp[t] - v;
}

// ---- scan step 3: add block offsets; set rowptr[N]=E ----
__global__ void scan3_kernel(int* __restrict__ rowptr, const int* __restrict__ bsum,
                             int N, int E) {
    int g = blockIdx.x * blockDim.x + threadIdx.x;
    if (g < N) rowptr[g] += bsum[g >> 10];
    if (g == 0) rowptr[N] = E;
}

// ---- CSR fill: adj[pos] = (src, -dis[src]*dis[dst]) packed; NT edge reads/adj writes ----
__global__ void fill_kernel(const int* __restrict__ src, const int* __restrict__ dst,
                            const float* __restrict__ dis, const int* __restrict__ rowptr,
                            int* __restrict__ fillc, int2* __restrict__ adj, int E) {
    int e = blockIdx.x * blockDim.x + threadIdx.x;
    if (e < E) {
        int s = __builtin_nontemporal_load(src + e);
        int d = __builtin_nontemporal_load(dst + e);
        int pos = rowptr[d] + atomicAdd(&fillc[d], 1);
        unsigned int wbits = (unsigned int)__float_as_int(-dis[s] * dis[d]);
        unsigned long long packed = (unsigned long long)(unsigned int)s |
                                    ((unsigned long long)wbits << 32);
        __builtin_nontemporal_store(packed,
            reinterpret_cast<unsigned long long*>(adj + pos));
    }
}

// ---- gemm0: out = b + x @ W0 (batched 4 nodes/wave, W0 in LDS) ----
__global__ __launch_bounds__(256, 8) void gemm0_kernel(
        const float* __restrict__ x, const float* __restrict__ W0,
        const float* __restrict__ bias, float* __restrict__ out, int N) {
    __shared__ float Ws[DD * DD];
    int t = threadIdx.x;
    {
        const float4* s4 = reinterpret_cast<const float4*>(W0);
        float4* d4 = reinterpret_cast<float4*>(Ws);
        #pragma unroll
        for (int i = 0; i < 4; ++i) d4[t + 256 * i] = s4[t + 256 * i];
    }
    __syncthreads();
    int nl = t >> 6, lane = t & 63;
    int node0 = (blockIdx.x * WPB + nl) * NPW;
    if (node0 >= N) return;
    int nv = min(NPW, N - node0);

    float bsv = bias[lane];
    float v[NPW], o[NPW];
    #pragma unroll
    for (int ni = 0; ni < NPW; ++ni) {
        v[ni] = (ni < nv) ? x[(long long)(node0 + ni) * DD + lane] : 0.f;
        o[ni] = bsv;
    }
    #pragma unroll 4
    for (int jj = 0; jj < DD; ++jj) {
        float w = Ws[jj * DD + lane];
        #pragma unroll
        for (int ni = 0; ni < NPW; ++ni) o[ni] += __shfl(v[ni], jj, 64) * w;
    }
    #pragma unroll
    for (int ni = 0; ni < NPW; ++ni)
        if (ni < nv) out[(long long)(node0 + ni) * DD + lane] = o[ni];
}

// ---- prop: Txk = scale*gather(h) - tx0 ; txout = Txk (optional) ; out += Txk@Wk ----
// Gather: 4 edge-slots x 16 lanes (float4 quarter-rows) with adj software
// prefetch (next pair loaded while current FMAs) -> 8 rows + 4 adj in flight.
// Redistribute via 1 ds_write_b128 + 1 ds_read_b32 per node; epilogue batched
// over NPW nodes with shfl broadcast.
// NOTE: txout may alias tx0 (own-index read-before-write) — no __restrict__ there.
__global__ __launch_bounds__(256, 7) void prop_kernel(
        const int* __restrict__ rowptr, const int2* __restrict__ adj,
        const float* __restrict__ h, const float* tx0,
        const float* __restrict__ Wk,
        float* txout, float* __restrict__ out,
        float scale, int N) {
    extern __shared__ float smem[];            // Ws[4096] = 16 KB
    float* Ws = smem;
    __shared__ float rows[WPB][DD];            // 1 KB, reused per node
    int t = threadIdx.x;
    {
        const float4* s4 = reinterpret_cast<const float4*>(Wk);
        float4* d4 = reinterpret_cast<float4*>(Ws);
        #pragma unroll
        for (int i = 0; i < 4; ++i) d4[t + 256 * i] = s4[t + 256 * i];
    }
    __syncthreads();

    int nl = t >> 6, lane = t & 63;
    int eg = lane >> 4;        // edge slot 0..3
    int q = lane & 15;         // quarter-row: columns 4q..4q+3
    int node0 = (blockIdx.x * WPB + nl) * NPW;
    if (node0 >= N) return;
    int nv = min(NPW, N - node0);

    const float4* h4 = reinterpret_cast<const float4*>(h);
    float v[NPW];
    #pragma unroll
    for (int ni = 0; ni < NPW; ++ni) v[ni] = 0.f;

    for (int ni = 0; ni < nv; ++ni) {
        int node = node0 + ni;
        int beg = rfl(rowptr[node]);
        int end = rfl(rowptr[node + 1]);
        float4 acc = make_float4(0.f, 0.f, 0.f, 0.f);
        int j = beg + eg;
        // prefetched current pair (weight bits 0 -> 0.0f, src 0 is a safe row)
        int2 e0 = (j < end) ? adj[j] : make_int2(0, 0);
        int2 e1 = (j + 4 < end) ? adj[j + 4] : make_int2(0, 0);
        while (j < end) {
            int jn = j + 8;
            int2 n0 = (jn < end) ? adj[jn] : make_int2(0, 0);
            int2 n1 = (jn + 4 < end) ? adj[jn + 4] : make_int2(0, 0);
            float4 g0 = h4[(long long)e0.x * 16 + q];
            float4 g1 = h4[(long long)e1.x * 16 + q];
            float w0 = __int_as_float(e0.y), w1 = __int_as_float(e1.y);
            acc.x += w0 * g0.x + w1 * g1.x;
            acc.y += w0 * g0.y + w1 * g1.y;
            acc.z += w0 * g0.z + w1 * g1.z;
            acc.w += w0 * g0.w + w1 * g1.w;
            e0 = n0; e1 = n1; j = jn;
        }
        // butterfly sum across the 4 edge-slot groups
        #pragma unroll
        for (int m = 16; m < 64; m <<= 1) {
            acc.x += __shfl_xor(acc.x, m, 64);
            acc.y += __shfl_xor(acc.y, m, 64);
            acc.z += __shfl_xor(acc.z, m, 64);
            acc.w += __shfl_xor(acc.w, m, 64);
        }
        // redistribute to lane=col layout via LDS roundtrip
        if (eg == 0) *reinterpret_cast<float4*>(&rows[nl][q * 4]) = acc;
        __builtin_amdgcn_wave_barrier();
        float racc = rows[nl][lane];
        __builtin_amdgcn_wave_barrier();       // rows reused next node

        long long base = (long long)node * DD;
        float t0v = tx0 ? tx0[base + lane] : 0.f;
        float val = scale * racc - t0v;
        if (txout) txout[base + lane] = val;
        v[ni] = val;
    }

    float o[NPW];
    #pragma unroll
    for (int ni = 0; ni < NPW; ++ni)
        o[ni] = (ni < nv) ? out[(long long)(node0 + ni) * DD + lane] : 0.f;

    #pragma unroll 4
    for (int jj = 0; jj < DD; ++jj) {
        float w = Ws[jj * DD + lane];
        #pragma unroll
        for (int ni = 0; ni < NPW; ++ni) o[ni] += __shfl(v[ni], jj, 64) * w;
    }

    #pragma unroll
    for (int ni = 0; ni < NPW; ++ni)
        if (ni < nv) out[(long long)(node0 + ni) * DD + lane] = o[ni];
}

extern "C" void kernel_launch(void* const* d_in, const int* in_sizes, int n_in,
                              void* d_out, int out_size, void* d_ws, size_t ws_size,
                              hipStream_t stream) {
    const float* x  = (const float*)d_in[0];
    const int*   ei = (const int*)d_in[1];
    const float* W  = (const float*)d_in[2];
    const float* b  = (const float*)d_in[3];
    float* out = (float*)d_out;

    const int N = in_sizes[0] / DD;
    const int E = in_sizes[1] / 2;
    const int K = in_sizes[2] / (DD * DD);
    const long long ND = (long long)N * DD;

    const int* src = ei;
    const int* dst = ei + E;

    float* ws    = (float*)d_ws;
    float* dis   = ws;                          // N floats
    int*   cnt   = (int*)(dis + N);             // N
    int*   fillc = cnt + N;                     // N
    int*   rowptr= fillc + N;                   // N+1
    int*   bsum  = rowptr + N + 1;              // 128
    int2*  adj   = (int2*)(bsum + 128);         // E (8B each, 8B-aligned)
    float* B1    = (float*)(adj + E);           // ND
    float* B2    = B1 + ND;                     // ND

    // zero dis, cnt, fillc in one memset (contiguous)
    hipMemsetAsync(dis, 0, (size_t)(3 * N) * sizeof(float), stream);

    degcnt_kernel<<<(E / 4 + 255) / 256, 256, 0, stream>>>(src, dst, dis, cnt, E);
    dis_kernel<<<(N + 255) / 256, 256, 0, stream>>>(dis, N);

    const int nb = (N + 1023) / 1024;           // <= 128 required
    scan1_kernel<<<nb, 1024, 0, stream>>>(cnt, rowptr, bsum, N);
    scan2_kernel<<<1, 128, 0, stream>>>(bsum, nb);
    scan3_kernel<<<(N + 255) / 256, 256, 0, stream>>>(rowptr, bsum, N, E);
    fill_kernel<<<(E + 255) / 256, 256, 0, stream>>>(src, dst, dis, rowptr, fillc,
                                                     adj, E);

    const int pgrid = (N + WPB * NPW - 1) / (WPB * NPW);
    const size_t ldsW = DD * DD * sizeof(float);   // 16 KB

    // out = b + x @ W0
    gemm0_kernel<<<pgrid, 256, 0, stream>>>(x, W, b, out, N);

    // k=1: Tx1 = prop(x) -> B1 ; out += Tx1 @ W1
    prop_kernel<<<pgrid, 256, ldsW, stream>>>(rowptr, adj, x, nullptr,
                                              W + DD * DD, B1, out, 1.0f, N);

    // k>=2: Txk = 2*prop(Tx1) - Tx0 ; out += Txk@Wk
    // Rotation invariant: target always aliases the NEXT tx0 (safe: tx0 is
    // read only at the owning thread's index before the write); never aliases h.
    const float* t0 = x;
    float* t1 = B1;
    float* tg = B2;
    for (int k = 2; k < K; ++k) {
        float* txw = (k == K - 1) ? nullptr : tg;   // last Tx is never read
        prop_kernel<<<pgrid, 256, ldsW, stream>>>(rowptr, adj, t1, t0,
                                                  W + (long long)k * DD * DD,
                                                  txw, out, 2.0f, N);
        const float* nt0 = t1;   // Tx_{k-1}
        float* nt1 = tg;         // Tx_k
        tg = (float*)nt0;        // next target aliases next tx0
        t0 = nt0;
        t1 = nt1;
    }
}

// Round 9
// 797.205 us; speedup vs baseline: 1.1028x; 1.0723x over previous
//
#include <hip/hip_runtime.h>

#define DD 64
#define NPW 4   // nodes per wave
#define WPB 4   // waves per block (256 threads)

typedef int vint4 __attribute__((ext_vector_type(4)));
typedef __fp16 half8v __attribute__((ext_vector_type(8)));

static __device__ __forceinline__ int rfl(int x) {
    return __builtin_amdgcn_readfirstlane(x);
}

// ---- degree over src (float, for dis) + count over dst (int, for CSR) ----
__global__ void degcnt_kernel(const int* __restrict__ src, const int* __restrict__ dst,
                              float* __restrict__ deg, int* __restrict__ cnt, int E) {
    int i = blockIdx.x * blockDim.x + threadIdx.x;
    int e0 = i * 4;
    if (e0 + 3 < E) {
        vint4 s = __builtin_nontemporal_load(reinterpret_cast<const vint4*>(src + e0));
        vint4 d = __builtin_nontemporal_load(reinterpret_cast<const vint4*>(dst + e0));
        atomicAdd(&deg[s.x], 1.0f); atomicAdd(&deg[s.y], 1.0f);
        atomicAdd(&deg[s.z], 1.0f); atomicAdd(&deg[s.w], 1.0f);
        atomicAdd(&cnt[d.x], 1); atomicAdd(&cnt[d.y], 1);
        atomicAdd(&cnt[d.z], 1); atomicAdd(&cnt[d.w], 1);
    } else {
        for (int e = e0; e < E; ++e) {
            atomicAdd(&deg[src[e]], 1.0f);
            atomicAdd(&cnt[dst[e]], 1);
        }
    }
}

// ---- dis = deg>0 ? rsqrt(deg) : 0 (in place) ----
__global__ void dis_kernel(float* __restrict__ deg, int N) {
    int n = blockIdx.x * blockDim.x + threadIdx.x;
    if (n < N) {
        float d = deg[n];
        deg[n] = (d > 0.0f) ? rsqrtf(d) : 0.0f;
    }
}

// ---- x -> fp16 copy ----
__global__ void cvt_kernel(const float* __restrict__ x, __fp16* __restrict__ xh,
                           long long n8) {
    long long i = (long long)blockIdx.x * blockDim.x + threadIdx.x;
    if (i < n8) {
        const float4* x4 = reinterpret_cast<const float4*>(x);
        float4 a = x4[i * 2], b = x4[i * 2 + 1];
        half8v h;
        h[0] = (__fp16)a.x; h[1] = (__fp16)a.y; h[2] = (__fp16)a.z; h[3] = (__fp16)a.w;
        h[4] = (__fp16)b.x; h[5] = (__fp16)b.y; h[6] = (__fp16)b.z; h[7] = (__fp16)b.w;
        reinterpret_cast<half8v*>(xh)[i] = h;
    }
}

// ---- scan step 1 ----
__global__ __launch_bounds__(1024) void scan1_kernel(const int* __restrict__ cnt,
                                                     int* __restrict__ rowptr,
                                                     int* __restrict__ bsum, int N) {
    __shared__ int tmp[1024];
    int t = threadIdx.x;
    int g = blockIdx.x * 1024 + t;
    int v = (g < N) ? cnt[g] : 0;
    tmp[t] = v;
    __syncthreads();
    for (int off = 1; off < 1024; off <<= 1) {
        int a = (t >= off) ? tmp[t - off] : 0;
        __syncthreads();
        tmp[t] += a;
        __syncthreads();
    }
    if (g < N) rowptr[g] = tmp[t] - v;
    if (t == 1023) bsum[blockIdx.x] = tmp[1023];
}

// ---- scan step 2 ----
__global__ __launch_bounds__(128) void scan2_kernel(int* __restrict__ data, int n) {
    __shared__ int tmp[128];
    int t = threadIdx.x;
    int v = (t < n) ? data[t] : 0;
    tmp[t] = v;
    __syncthreads();
    for (int off = 1; off < 128; off <<= 1) {
        int a = (t >= off) ? tmp[t - off] : 0;
        __syncthreads();
        tmp[t] += a;
        __syncthreads();
    }
    if (t < n) data[t] = tmp[t] - v;
}

// ---- scan step 3 ----
__global__ void scan3_kernel(int* __restrict__ rowptr, const int* __restrict__ bsum,
                             int N, int E) {
    int g = blockIdx.x * blockDim.x + threadIdx.x;
    if (g < N) rowptr[g] += bsum[g >> 10];
    if (g == 0) rowptr[N] = E;
}

// ---- CSR fill ----
__global__ void fill_kernel(const int* __restrict__ src, const int* __restrict__ dst,
                            const float* __restrict__ dis, const int* __restrict__ rowptr,
                            int* __restrict__ fillc, int2* __restrict__ adj, int E) {
    int e = blockIdx.x * blockDim.x + threadIdx.x;
    if (e < E) {
        int s = __builtin_nontemporal_load(src + e);
        int d = __builtin_nontemporal_load(dst + e);
        int pos = rowptr[d] + atomicAdd(&fillc[d], 1);
        unsigned int wbits = (unsigned int)__float_as_int(-dis[s] * dis[d]);
        unsigned long long packed = (unsigned long long)(unsigned int)s |
                                    ((unsigned long long)wbits << 32);
        __builtin_nontemporal_store(packed,
            reinterpret_cast<unsigned long long*>(adj + pos));
    }
}

// ---- gemm0: out = b + x @ W0 (fp32 x, W0 in LDS) ----
__global__ __launch_bounds__(256, 8) void gemm0_kernel(
        const float* __restrict__ x, const float* __restrict__ W0,
        const float* __restrict__ bias, float* __restrict__ out, int N) {
    __shared__ float Ws[DD * DD];
    int t = threadIdx.x;
    {
        const float4* s4 = reinterpret_cast<const float4*>(W0);
        float4* d4 = reinterpret_cast<float4*>(Ws);
        #pragma unroll
        for (int i = 0; i < 4; ++i) d4[t + 256 * i] = s4[t + 256 * i];
    }
    __syncthreads();
    int nl = t >> 6, lane = t & 63;
    int node0 = (blockIdx.x * WPB + nl) * NPW;
    if (node0 >= N) return;
    int nv = min(NPW, N - node0);

    float bsv = bias[lane];
    float v[NPW], o[NPW];
    #pragma unroll
    for (int ni = 0; ni < NPW; ++ni) {
        v[ni] = (ni < nv) ? x[(long long)(node0 + ni) * DD + lane] : 0.f;
        o[ni] = bsv;
    }
    #pragma unroll 4
    for (int jj = 0; jj < DD; ++jj) {
        float w = Ws[jj * DD + lane];
        #pragma unroll
        for (int ni = 0; ni < NPW; ++ni) o[ni] += __shfl(v[ni], jj, 64) * w;
    }
    #pragma unroll
    for (int ni = 0; ni < NPW; ++ni)
        if (ni < nv) out[(long long)(node0 + ni) * DD + lane] = o[ni];
}

// ---- prop (fp16 state): v = scale*gather(h_h) - t0_h ; txout_h = fp16(v) ;
//      out += v @ Wk  (fp32 accum throughout) ----
// Gather: 8 edge-slots x 8 lanes, each lane one half8 (16 B) = 128 B/row,
// 2-deep adj prefetch -> 16 rows in flight/wave.
// NOTE: txout_h may alias t0_h (own-index read-before-write) — no __restrict__.
__global__ __launch_bounds__(256, 8) void prop_kernel(
        const int* __restrict__ rowptr, const int2* __restrict__ adj,
        const __fp16* __restrict__ h, const __fp16* t0h,
        const float* __restrict__ Wk,
        __fp16* txouth, float* __restrict__ out,
        float scale, int N) {
    extern __shared__ float smem[];            // Ws[4096] = 16 KB
    float* Ws = smem;
    __shared__ float rows[WPB][DD];
    int t = threadIdx.x;
    {
        const float4* s4 = reinterpret_cast<const float4*>(Wk);
        float4* d4 = reinterpret_cast<float4*>(Ws);
        #pragma unroll
        for (int i = 0; i < 4; ++i) d4[t + 256 * i] = s4[t + 256 * i];
    }
    __syncthreads();

    int nl = t >> 6, lane = t & 63;
    int s = lane >> 3;         // edge slot 0..7
    int q = lane & 7;          // half8 chunk: columns 8q..8q+7
    int node0 = (blockIdx.x * WPB + nl) * NPW;
    if (node0 >= N) return;
    int nv = min(NPW, N - node0);

    const half8v* h8 = reinterpret_cast<const half8v*>(h);
    float v[NPW];
    #pragma unroll
    for (int ni = 0; ni < NPW; ++ni) v[ni] = 0.f;

    for (int ni = 0; ni < nv; ++ni) {
        int node = node0 + ni;
        int beg = rfl(rowptr[node]);
        int end = rfl(rowptr[node + 1]);
        float acc[8];
        #pragma unroll
        for (int i = 0; i < 8; ++i) acc[i] = 0.f;
        int j = beg + s;
        int2 e0 = (j < end) ? adj[j] : make_int2(0, 0);
        int2 e1 = (j + 8 < end) ? adj[j + 8] : make_int2(0, 0);
        while (j < end) {
            int jn = j + 16;
            int2 n0 = (jn < end) ? adj[jn] : make_int2(0, 0);
            int2 n1 = (jn + 8 < end) ? adj[jn + 8] : make_int2(0, 0);
            half8v g0 = h8[(long long)e0.x * 8 + q];
            half8v g1 = h8[(long long)e1.x * 8 + q];
            float w0 = __int_as_float(e0.y), w1 = __int_as_float(e1.y);
            #pragma unroll
            for (int i = 0; i < 8; ++i)
                acc[i] += w0 * (float)g0[i] + w1 * (float)g1[i];
            e0 = n0; e1 = n1; j = jn;
        }
        // butterfly sum across the 8 edge-slot groups
        #pragma unroll
        for (int m = 8; m < 64; m <<= 1) {
            #pragma unroll
            for (int i = 0; i < 8; ++i) acc[i] += __shfl_xor(acc[i], m, 64);
        }
        // redistribute: slot-0 lanes (lane<8) hold cols 8q..8q+7 -> LDS -> lane=col
        if (s == 0) {
            #pragma unroll
            for (int i = 0; i < 8; ++i) rows[nl][q * 8 + i] = acc[i];
        }
        __builtin_amdgcn_wave_barrier();
        float racc = rows[nl][lane];
        __builtin_amdgcn_wave_barrier();       // rows reused next node

        long long base = (long long)node * DD;
        float t0v = t0h ? (float)t0h[base + lane] : 0.f;
        float val = scale * racc - t0v;
        if (txouth) txouth[base + lane] = (__fp16)val;
        v[ni] = val;
    }

    float o[NPW];
    #pragma unroll
    for (int ni = 0; ni < NPW; ++ni)
        o[ni] = (ni < nv) ? out[(long long)(node0 + ni) * DD + lane] : 0.f;

    #pragma unroll 4
    for (int jj = 0; jj < DD; ++jj) {
        float w = Ws[jj * DD + lane];
        #pragma unroll
        for (int ni = 0; ni < NPW; ++ni) o[ni] += __shfl(v[ni], jj, 64) * w;
    }

    #pragma unroll
    for (int ni = 0; ni < NPW; ++ni)
        if (ni < nv) out[(long long)(node0 + ni) * DD + lane] = o[ni];
}

extern "C" void kernel_launch(void* const* d_in, const int* in_sizes, int n_in,
                              void* d_out, int out_size, void* d_ws, size_t ws_size,
                              hipStream_t stream) {
    const float* x  = (const float*)d_in[0];
    const int*   ei = (const int*)d_in[1];
    const float* W  = (const float*)d_in[2];
    const float* b  = (const float*)d_in[3];
    float* out = (float*)d_out;

    const int N = in_sizes[0] / DD;
    const int E = in_sizes[1] / 2;
    const int K = in_sizes[2] / (DD * DD);
    const long long ND = (long long)N * DD;

    const int* src = ei;
    const int* dst = ei + E;

    float*  ws    = (float*)d_ws;
    float*  dis   = ws;                          // N floats
    int*    cnt   = (int*)(dis + N);             // N
    int*    fillc = cnt + N;                     // N
    int*    rowptr= fillc + N;                   // N+1
    int*    bsum  = rowptr + N + 1;              // 128
    int2*   adj   = (int2*)(bsum + 128);         // E int2
    __fp16* Xh    = (__fp16*)(adj + E);          // ND halves
    __fp16* B1h   = Xh + ND;                     // ND
    __fp16* B2h   = B1h + ND;                    // ND

    // zero dis, cnt, fillc in one memset (contiguous)
    hipMemsetAsync(dis, 0, (size_t)(3 * N) * sizeof(float), stream);

    degcnt_kernel<<<(E / 4 + 255) / 256, 256, 0, stream>>>(src, dst, dis, cnt, E);
    dis_kernel<<<(N + 255) / 256, 256, 0, stream>>>(dis, N);

    const long long n8 = ND / 8;
    cvt_kernel<<<(int)((n8 + 255) / 256), 256, 0, stream>>>(x, Xh, n8);

    const int nb = (N + 1023) / 1024;           // <= 128 required
    scan1_kernel<<<nb, 1024, 0, stream>>>(cnt, rowptr, bsum, N);
    scan2_kernel<<<1, 128, 0, stream>>>(bsum, nb);
    scan3_kernel<<<(N + 255) / 256, 256, 0, stream>>>(rowptr, bsum, N, E);
    fill_kernel<<<(E + 255) / 256, 256, 0, stream>>>(src, dst, dis, rowptr, fillc,
                                                     adj, E);

    const int pgrid = (N + WPB * NPW - 1) / (WPB * NPW);
    const size_t ldsW = DD * DD * sizeof(float);   // 16 KB

    // out = b + x @ W0 (fp32 path)
    gemm0_kernel<<<pgrid, 256, 0, stream>>>(x, W, b, out, N);

    // k=1: Tx1 = prop(x) -> B1h ; out += Tx1 @ W1
    prop_kernel<<<pgrid, 256, ldsW, stream>>>(rowptr, adj, Xh, nullptr,
                                              W + DD * DD, B1h, out, 1.0f, N);

    // k>=2: Txk = 2*prop(Tx1) - Tx0 ; out += Txk@Wk
    // Buffers rotate among {Xh, B1h, B2h}; target always aliases next tx0
    // (safe: own-index read-before-write); never aliases the gather source.
    // Xh is free to overwrite after k=2 (only k=1 gathers from it; gemm0 reads fp32 x).
    const __fp16* t0 = Xh;
    __fp16* t1 = B1h;
    __fp16* tg = B2h;
    for (int k = 2; k < K; ++k) {
        __fp16* txw = (k == K - 1) ? nullptr : tg;   // last Tx never read
        prop_kernel<<<pgrid, 256, ldsW, stream>>>(rowptr, adj, t1, t0,
                                                  W + (long long)k * DD * DD,
                                                  txw, out, 2.0f, N);
        const __fp16* nt0 = t1;   // Tx_{k-1}
        __fp16* nt1 = tg;         // Tx_k
        tg = (__fp16*)nt0;        // next target aliases next tx0
        t0 = nt0;
        t1 = nt1;
    }
}

// Round 10
// 658.132 us; speedup vs baseline: 1.3358x; 1.2113x over previous
//
#include <hip/hip_runtime.h>

#define DD 64
#define NPW 4    // nodes per wave (gather)
#define WPB 4    // waves per block
#define NPB 16   // nodes per block
#define ASTR 72  // halves per A_lds row (64 + 8 pad -> conflict-free frag reads)

typedef int vint4 __attribute__((ext_vector_type(4)));
typedef _Float16 f16x8 __attribute__((ext_vector_type(8)));
typedef float f32x4 __attribute__((ext_vector_type(4)));

static __device__ __forceinline__ int rfl(int x) {
    return __builtin_amdgcn_readfirstlane(x);
}

// ---- degree over src (float) + count over dst (int) ----
__global__ void degcnt_kernel(const int* __restrict__ src, const int* __restrict__ dst,
                              float* __restrict__ deg, int* __restrict__ cnt, int E) {
    int i = blockIdx.x * blockDim.x + threadIdx.x;
    int e0 = i * 4;
    if (e0 + 3 < E) {
        vint4 s = __builtin_nontemporal_load(reinterpret_cast<const vint4*>(src + e0));
        vint4 d = __builtin_nontemporal_load(reinterpret_cast<const vint4*>(dst + e0));
        atomicAdd(&deg[s.x], 1.0f); atomicAdd(&deg[s.y], 1.0f);
        atomicAdd(&deg[s.z], 1.0f); atomicAdd(&deg[s.w], 1.0f);
        atomicAdd(&cnt[d.x], 1); atomicAdd(&cnt[d.y], 1);
        atomicAdd(&cnt[d.z], 1); atomicAdd(&cnt[d.w], 1);
    } else {
        for (int e = e0; e < E; ++e) {
            atomicAdd(&deg[src[e]], 1.0f);
            atomicAdd(&cnt[dst[e]], 1);
        }
    }
}

__global__ void dis_kernel(float* __restrict__ deg, int N) {
    int n = blockIdx.x * blockDim.x + threadIdx.x;
    if (n < N) {
        float d = deg[n];
        deg[n] = (d > 0.0f) ? rsqrtf(d) : 0.0f;
    }
}

// ---- x -> fp16 ----
__global__ void cvt_kernel(const float* __restrict__ x, _Float16* __restrict__ xh,
                           long long n8) {
    long long i = (long long)blockIdx.x * blockDim.x + threadIdx.x;
    if (i < n8) {
        const float4* x4 = reinterpret_cast<const float4*>(x);
        float4 a = x4[i * 2], b = x4[i * 2 + 1];
        f16x8 h;
        h[0] = (_Float16)a.x; h[1] = (_Float16)a.y; h[2] = (_Float16)a.z; h[3] = (_Float16)a.w;
        h[4] = (_Float16)b.x; h[5] = (_Float16)b.y; h[6] = (_Float16)b.z; h[7] = (_Float16)b.w;
        reinterpret_cast<f16x8*>(xh)[i] = h;
    }
}

// ---- scans ----
__global__ __launch_bounds__(1024) void scan1_kernel(const int* __restrict__ cnt,
                                                     int* __restrict__ rowptr,
                                                     int* __restrict__ bsum, int N) {
    __shared__ int tmp[1024];
    int t = threadIdx.x;
    int g = blockIdx.x * 1024 + t;
    int v = (g < N) ? cnt[g] : 0;
    tmp[t] = v;
    __syncthreads();
    for (int off = 1; off < 1024; off <<= 1) {
        int a = (t >= off) ? tmp[t - off] : 0;
        __syncthreads();
        tmp[t] += a;
        __syncthreads();
    }
    if (g < N) rowptr[g] = tmp[t] - v;
    if (t == 1023) bsum[blockIdx.x] = tmp[1023];
}

__global__ __launch_bounds__(128) void scan2_kernel(int* __restrict__ data, int n) {
    __shared__ int tmp[128];
    int t = threadIdx.x;
    int v = (t < n) ? data[t] : 0;
    tmp[t] = v;
    __syncthreads();
    for (int off = 1; off < 128; off <<= 1) {
        int a = (t >= off) ? tmp[t - off] : 0;
        __syncthreads();
        tmp[t] += a;
        __syncthreads();
    }
    if (t < n) data[t] = tmp[t] - v;
}

__global__ void scan3_kernel(int* __restrict__ rowptr, const int* __restrict__ bsum,
                             int N, int E) {
    int g = blockIdx.x * blockDim.x + threadIdx.x;
    if (g < N) rowptr[g] += bsum[g >> 10];
    if (g == 0) rowptr[N] = E;
}

// ---- CSR fill ----
__global__ void fill_kernel(const int* __restrict__ src, const int* __restrict__ dst,
                            const float* __restrict__ dis, const int* __restrict__ rowptr,
                            int* __restrict__ fillc, int2* __restrict__ adj, int E) {
    int e = blockIdx.x * blockDim.x + threadIdx.x;
    if (e < E) {
        int s = __builtin_nontemporal_load(src + e);
        int d = __builtin_nontemporal_load(dst + e);
        int pos = rowptr[d] + atomicAdd(&fillc[d], 1);
        unsigned int wbits = (unsigned int)__float_as_int(-dis[s] * dis[d]);
        unsigned long long packed = (unsigned long long)(unsigned int)s |
                                    ((unsigned long long)wbits << 32);
        __builtin_nontemporal_store(packed,
            reinterpret_cast<unsigned long long*>(adj + pos));
    }
}

// ---- prop: v = scale*gather(h) - tx0 ; txout = fp16(v) ; out (+)= v@Wk [+ x@W0 + b] ----
// Gather (unchanged): 8 edge-slots x 8 lanes x half8, 2-deep adj prefetch, butterfly.
// Epilogue: MFMA. Block stages 16 node-rows (fp16) into padded LDS A-tile; wave nl
// computes out col-tile [16 x 16] via mfma_f32_16x16x32_f16 (W frags in registers;
// A/B share the same k<->lane mapping so any consistent permutation is correct).
// NOTE: txouth may alias t0h (own-index read-before-write) — no __restrict__ there.
__global__ __launch_bounds__(256, 8) void prop_kernel(
        const int* __restrict__ rowptr, const int2* __restrict__ adj,
        const _Float16* __restrict__ h, const _Float16* t0h,
        const float* __restrict__ Wk, const float* __restrict__ W0,
        const float* __restrict__ bias,
        _Float16* txouth, float* out, float scale, int N) {
    __shared__ _Float16 A_lds[NPB][ASTR];
    __shared__ _Float16 X_lds[NPB][ASTR];   // used on init (W0) pass only
    int t = threadIdx.x;
    int nl = t >> 6, lane = t & 63;
    int ct = nl;               // this wave's output col-tile
    int lr = lane & 15;        // frag m/n index
    int lk = lane >> 4;        // frag k-group

    // --- B-frags: Wk (and W0) columns ct*16+lr, fp16, k = kt*32 + lk*8 + i ---
    f16x8 bfrag[2], bfrag0[2];
    #pragma unroll
    for (int kt = 0; kt < 2; ++kt) {
        #pragma unroll
        for (int i = 0; i < 8; ++i) {
            int r = kt * 32 + lk * 8 + i;
            bfrag[kt][i] = (_Float16)Wk[r * DD + ct * 16 + lr];
        }
    }
    if (W0) {
        #pragma unroll
        for (int kt = 0; kt < 2; ++kt) {
            #pragma unroll
            for (int i = 0; i < 8; ++i) {
                int r = kt * 32 + lk * 8 + i;
                bfrag0[kt][i] = (_Float16)W0[r * DD + ct * 16 + lr];
            }
        }
    }

    int s = lane >> 3;         // edge slot 0..7
    int q = lane & 7;          // half8 chunk: columns 8q..8q+7
    int node0 = blockIdx.x * NPB + nl * NPW;
    int nv = min(NPW, max(0, N - node0));
    const f16x8* h8 = reinterpret_cast<const f16x8*>(h);

    for (int ni = 0; ni < nv; ++ni) {
        int node = node0 + ni;
        int beg = rfl(rowptr[node]);
        int end = rfl(rowptr[node + 1]);
        float acc[8];
        #pragma unroll
        for (int i = 0; i < 8; ++i) acc[i] = 0.f;
        int j = beg + s;
        int2 e0 = (j < end) ? adj[j] : make_int2(0, 0);
        int2 e1 = (j + 8 < end) ? adj[j + 8] : make_int2(0, 0);
        while (j < end) {
            int jn = j + 16;
            int2 n0 = (jn < end) ? adj[jn] : make_int2(0, 0);
            int2 n1 = (jn + 8 < end) ? adj[jn + 8] : make_int2(0, 0);
            f16x8 g0 = h8[(long long)e0.x * 8 + q];
            f16x8 g1 = h8[(long long)e1.x * 8 + q];
            float w0 = __int_as_float(e0.y), w1 = __int_as_float(e1.y);
            #pragma unroll
            for (int i = 0; i < 8; ++i)
                acc[i] += w0 * (float)g0[i] + w1 * (float)g1[i];
            e0 = n0; e1 = n1; j = jn;
        }
        #pragma unroll
        for (int m = 8; m < 64; m <<= 1) {
            #pragma unroll
            for (int i = 0; i < 8; ++i) acc[i] += __shfl_xor(acc[i], m, 64);
        }
        // lanes 0..7 finish this node: tx0, txout store, A-tile stage (+x stage on init)
        if (s == 0) {
            long long base = (long long)node * DD + q * 8;
            float val[8];
            if (t0h) {
                f16x8 t0v = *reinterpret_cast<const f16x8*>(t0h + base);
                #pragma unroll
                for (int i = 0; i < 8; ++i) val[i] = scale * acc[i] - (float)t0v[i];
            } else {
                #pragma unroll
                for (int i = 0; i < 8; ++i) val[i] = scale * acc[i];
            }
            f16x8 vh;
            #pragma unroll
            for (int i = 0; i < 8; ++i) vh[i] = (_Float16)val[i];
            if (txouth) *reinterpret_cast<f16x8*>(txouth + base) = vh;
            *reinterpret_cast<f16x8*>(&A_lds[nl * NPW + ni][q * 8]) = vh;
            if (W0) {
                f16x8 xv = h8[(long long)node * 8 + q];
                *reinterpret_cast<f16x8*>(&X_lds[nl * NPW + ni][q * 8]) = xv;
            }
        }
    }
    __syncthreads();

    // --- MFMA epilogue: D[16 nodes x 16 cols] for col-tile ct ---
    f32x4 d = {0.f, 0.f, 0.f, 0.f};
    f16x8 a0 = *reinterpret_cast<const f16x8*>(&A_lds[lr][lk * 8]);
    f16x8 a1 = *reinterpret_cast<const f16x8*>(&A_lds[lr][32 + lk * 8]);
    d = __builtin_amdgcn_mfma_f32_16x16x32_f16(a0, bfrag[0], d, 0, 0, 0);
    d = __builtin_amdgcn_mfma_f32_16x16x32_f16(a1, bfrag[1], d, 0, 0, 0);
    if (W0) {
        f16x8 x0 = *reinterpret_cast<const f16x8*>(&X_lds[lr][lk * 8]);
        f16x8 x1 = *reinterpret_cast<const f16x8*>(&X_lds[lr][32 + lk * 8]);
        d = __builtin_amdgcn_mfma_f32_16x16x32_f16(x0, bfrag0[0], d, 0, 0, 0);
        d = __builtin_amdgcn_mfma_f32_16x16x32_f16(x1, bfrag0[1], d, 0, 0, 0);
    }
    int nvb = min(NPB, N - blockIdx.x * NPB);
    int col = ct * 16 + lr;
    float bv = W0 ? bias[col] : 0.f;
    #pragma unroll
    for (int r = 0; r < 4; ++r) {
        int row = lk * 4 + r;
        if (row < nvb) {
            long long o = (long long)(blockIdx.x * NPB + row) * DD + col;
            out[o] = (W0 ? bv : out[o]) + d[r];
        }
    }
}

extern "C" void kernel_launch(void* const* d_in, const int* in_sizes, int n_in,
                              void* d_out, int out_size, void* d_ws, size_t ws_size,
                              hipStream_t stream) {
    const float* x  = (const float*)d_in[0];
    const int*   ei = (const int*)d_in[1];
    const float* W  = (const float*)d_in[2];
    const float* b  = (const float*)d_in[3];
    float* out = (float*)d_out;

    const int N = in_sizes[0] / DD;
    const int E = in_sizes[1] / 2;
    const int K = in_sizes[2] / (DD * DD);
    const long long ND = (long long)N * DD;

    const int* src = ei;
    const int* dst = ei + E;

    float*     ws    = (float*)d_ws;
    float*     dis   = ws;                          // N floats
    int*       cnt   = (int*)(dis + N);             // N
    int*       fillc = cnt + N;                     // N
    int*       rowptr= fillc + N;                   // N+1
    int*       bsum  = rowptr + N + 1;              // 128
    int2*      adj   = (int2*)(bsum + 128);         // E int2
    _Float16*  Xh    = (_Float16*)(adj + E);        // ND halves
    _Float16*  B1h   = Xh + ND;                     // ND
    _Float16*  B2h   = B1h + ND;                    // ND

    (void)hipMemsetAsync(dis, 0, (size_t)(3 * N) * sizeof(float), stream);

    degcnt_kernel<<<(E / 4 + 255) / 256, 256, 0, stream>>>(src, dst, dis, cnt, E);
    dis_kernel<<<(N + 255) / 256, 256, 0, stream>>>(dis, N);

    const long long n8 = ND / 8;
    cvt_kernel<<<(int)((n8 + 255) / 256), 256, 0, stream>>>(x, Xh, n8);

    const int nb = (N + 1023) / 1024;           // <= 128 required
    scan1_kernel<<<nb, 1024, 0, stream>>>(cnt, rowptr, bsum, N);
    scan2_kernel<<<1, 128, 0, stream>>>(bsum, nb);
    scan3_kernel<<<(N + 255) / 256, 256, 0, stream>>>(rowptr, bsum, N, E);
    fill_kernel<<<(E + 255) / 256, 256, 0, stream>>>(src, dst, dis, rowptr, fillc,
                                                     adj, E);

    const int pgrid = (N + NPB - 1) / NPB;

    // k=0 + k=1 fused: out = b + x@W0 + Tx1@W1 ; B1h = Tx1 = prop(x)
    prop_kernel<<<pgrid, 256, 0, stream>>>(rowptr, adj, Xh, nullptr,
                                           W + DD * DD, W, b,
                                           B1h, out, 1.0f, N);

    // k>=2: Txk = 2*prop(Tx1) - Tx0 ; out += Txk@Wk
    // Rotation: target always aliases next tx0 (own-index read-before-write);
    // never aliases the gather source.
    const _Float16* t0 = Xh;
    _Float16* t1 = B1h;
    _Float16* tg = B2h;
    for (int k = 2; k < K; ++k) {
        _Float16* txw = (k == K - 1) ? nullptr : tg;   // last Tx never read
        prop_kernel<<<pgrid, 256, 0, stream>>>(rowptr, adj, t1, t0,
                                               W + (long long)k * DD * DD, nullptr, b,
                                               txw, out, 2.0f, N);
        const _Float16* nt0 = t1;
        _Float16* nt1 = tg;
        tg = (_Float16*)nt0;
        t0 = nt0;
        t1 = nt1;
    }
}

// Round 11
// 632.372 us; speedup vs baseline: 1.3902x; 1.0407x over previous
//
#include <hip/hip_runtime.h>

#define DD 64
#define NPW 4    // nodes per wave (gather)
#define WPB 4    // waves per block
#define NPB 16   // nodes per block
#define ASTR 72  // halves per A_lds row (64 + 8 pad -> conflict-free frag reads)

typedef int vint4 __attribute__((ext_vector_type(4)));
typedef _Float16 f16x8 __attribute__((ext_vector_type(8)));
typedef float f32x4 __attribute__((ext_vector_type(4)));

static __device__ __forceinline__ int rfl(int x) {
    return __builtin_amdgcn_readfirstlane(x);
}

// ---- histograms: degi[src]++ (int), eoff[e] = cnt[dst[e]]++ (CSR offset) ----
__global__ void degcnt_kernel(const int* __restrict__ src, const int* __restrict__ dst,
                              int* __restrict__ degi, int* __restrict__ cnt,
                              int* __restrict__ eoff, int E) {
    int i = blockIdx.x * blockDim.x + threadIdx.x;
    int e0 = i * 4;
    if (e0 + 3 < E) {
        vint4 s = __builtin_nontemporal_load(reinterpret_cast<const vint4*>(src + e0));
        vint4 d = __builtin_nontemporal_load(reinterpret_cast<const vint4*>(dst + e0));
        vint4 o;
        o.x = atomicAdd(&cnt[d.x], 1);
        o.y = atomicAdd(&cnt[d.y], 1);
        o.z = atomicAdd(&cnt[d.z], 1);
        o.w = atomicAdd(&cnt[d.w], 1);
        atomicAdd(&degi[s.x], 1); atomicAdd(&degi[s.y], 1);
        atomicAdd(&degi[s.z], 1); atomicAdd(&degi[s.w], 1);
        __builtin_nontemporal_store(o, reinterpret_cast<vint4*>(eoff + e0));
    } else {
        for (int e = e0; e < E; ++e) {
            atomicAdd(&degi[src[e]], 1);
            eoff[e] = atomicAdd(&cnt[dst[e]], 1);
        }
    }
}

// ---- dis = deg>0 ? rsqrt(deg) : 0 ----
__global__ void dis_kernel(const int* __restrict__ degi, float* __restrict__ dis, int N) {
    int n = blockIdx.x * blockDim.x + threadIdx.x;
    if (n < N) {
        int d = degi[n];
        dis[n] = (d > 0) ? rsqrtf((float)d) : 0.0f;
    }
}

// ---- x -> fp16 ----
__global__ void cvt_kernel(const float* __restrict__ x, _Float16* __restrict__ xh,
                           long long n8) {
    long long i = (long long)blockIdx.x * blockDim.x + threadIdx.x;
    if (i < n8) {
        const float4* x4 = reinterpret_cast<const float4*>(x);
        float4 a = x4[i * 2], b = x4[i * 2 + 1];
        f16x8 h;
        h[0] = (_Float16)a.x; h[1] = (_Float16)a.y; h[2] = (_Float16)a.z; h[3] = (_Float16)a.w;
        h[4] = (_Float16)b.x; h[5] = (_Float16)b.y; h[6] = (_Float16)b.z; h[7] = (_Float16)b.w;
        reinterpret_cast<f16x8*>(xh)[i] = h;
    }
}

// ---- scans ----
__global__ __launch_bounds__(1024) void scan1_kernel(const int* __restrict__ cnt,
                                                     int* __restrict__ rowptr,
                                                     int* __restrict__ bsum, int N) {
    __shared__ int tmp[1024];
    int t = threadIdx.x;
    int g = blockIdx.x * 1024 + t;
    int v = (g < N) ? cnt[g] : 0;
    tmp[t] = v;
    __syncthreads();
    for (int off = 1; off < 1024; off <<= 1) {
        int a = (t >= off) ? tmp[t - off] : 0;
        __syncthreads();
        tmp[t] += a;
        __syncthreads();
    }
    if (g < N) rowptr[g] = tmp[t] - v;
    if (t == 1023) bsum[blockIdx.x] = tmp[1023];
}

__global__ __launch_bounds__(128) void scan2_kernel(int* __restrict__ data, int n) {
    __shared__ int tmp[128];
    int t = threadIdx.x;
    int v = (t < n) ? data[t] : 0;
    tmp[t] = v;
    __syncthreads();
    for (int off = 1; off < 128; off <<= 1) {
        int a = (t >= off) ? tmp[t - off] : 0;
        __syncthreads();
        tmp[t] += a;
        __syncthreads();
    }
    if (t < n) data[t] = tmp[t] - v;
}

__global__ void scan3_kernel(int* __restrict__ rowptr, const int* __restrict__ bsum,
                             int N, int E) {
    int g = blockIdx.x * blockDim.x + threadIdx.x;
    if (g < N) rowptr[g] += bsum[g >> 10];
    if (g == 0) rowptr[N] = E;
}

// ---- CSR fill (no atomics: pos = rowptr[dst] + eoff[e]) ----
__global__ void fill_kernel(const int* __restrict__ src, const int* __restrict__ dst,
                            const float* __restrict__ dis, const int* __restrict__ rowptr,
                            const int* __restrict__ eoff, int2* __restrict__ adj, int E) {
    int e = blockIdx.x * blockDim.x + threadIdx.x;
    if (e < E) {
        int s = __builtin_nontemporal_load(src + e);
        int d = __builtin_nontemporal_load(dst + e);
        int off = __builtin_nontemporal_load(eoff + e);
        int pos = rowptr[d] + off;
        unsigned int wbits = (unsigned int)__float_as_int(-dis[s] * dis[d]);
        unsigned long long packed = (unsigned long long)(unsigned int)s |
                                    ((unsigned long long)wbits << 32);
        __builtin_nontemporal_store(packed,
            reinterpret_cast<unsigned long long*>(adj + pos));
    }
}

// ---- prop: v = scale*gather(h) - tx0 ; txout = fp16(v) ; out (+)= v@Wk [+ x@W0 + b] ----
// Gather: 8 edge-slots x 8 lanes x half8, 2-deep adj prefetch, butterfly reduce.
// Epilogue: MFMA (16 node-rows staged in padded LDS; wave = one 16x16 col-tile).
// NOTE: txouth may alias t0h (own-index read-before-write) — no __restrict__ there.
__global__ __launch_bounds__(256, 8) void prop_kernel(
        const int* __restrict__ rowptr, const int2* __restrict__ adj,
        const _Float16* __restrict__ h, const _Float16* t0h,
        const float* __restrict__ Wk, const float* __restrict__ W0,
        const float* __restrict__ bias,
        _Float16* txouth, float* out, float scale, int N) {
    __shared__ _Float16 A_lds[NPB][ASTR];
    __shared__ _Float16 X_lds[NPB][ASTR];   // used on init (W0) pass only
    int t = threadIdx.x;
    int nl = t >> 6, lane = t & 63;
    int ct = nl;               // this wave's output col-tile
    int lr = lane & 15;        // frag m/n index
    int lk = lane >> 4;        // frag k-group

    // --- B-frags: Wk (and W0) columns ct*16+lr, fp16, k = kt*32 + lk*8 + i ---
    f16x8 bfrag[2], bfrag0[2];
    #pragma unroll
    for (int kt = 0; kt < 2; ++kt) {
        #pragma unroll
        for (int i = 0; i < 8; ++i) {
            int r = kt * 32 + lk * 8 + i;
            bfrag[kt][i] = (_Float16)Wk[r * DD + ct * 16 + lr];
        }
    }
    if (W0) {
        #pragma unroll
        for (int kt = 0; kt < 2; ++kt) {
            #pragma unroll
            for (int i = 0; i < 8; ++i) {
                int r = kt * 32 + lk * 8 + i;
                bfrag0[kt][i] = (_Float16)W0[r * DD + ct * 16 + lr];
            }
        }
    }

    int s = lane >> 3;         // edge slot 0..7
    int q = lane & 7;          // half8 chunk: columns 8q..8q+7
    int node0 = blockIdx.x * NPB + nl * NPW;
    int nv = min(NPW, max(0, N - node0));
    const f16x8* h8 = reinterpret_cast<const f16x8*>(h);

    for (int ni = 0; ni < nv; ++ni) {
        int node = node0 + ni;
        int beg = rfl(rowptr[node]);
        int end = rfl(rowptr[node + 1]);
        float acc[8];
        #pragma unroll
        for (int i = 0; i < 8; ++i) acc[i] = 0.f;
        int j = beg + s;
        int2 e0 = (j < end) ? adj[j] : make_int2(0, 0);
        int2 e1 = (j + 8 < end) ? adj[j + 8] : make_int2(0, 0);
        while (j < end) {
            int jn = j + 16;
            int2 n0 = (jn < end) ? adj[jn] : make_int2(0, 0);
            int2 n1 = (jn + 8 < end) ? adj[jn + 8] : make_int2(0, 0);
            f16x8 g0 = h8[(long long)e0.x * 8 + q];
            f16x8 g1 = h8[(long long)e1.x * 8 + q];
            float w0 = __int_as_float(e0.y), w1 = __int_as_float(e1.y);
            #pragma unroll
            for (int i = 0; i < 8; ++i)
                acc[i] += w0 * (float)g0[i] + w1 * (float)g1[i];
            e0 = n0; e1 = n1; j = jn;
        }
        #pragma unroll
        for (int m = 8; m < 64; m <<= 1) {
            #pragma unroll
            for (int i = 0; i < 8; ++i) acc[i] += __shfl_xor(acc[i], m, 64);
        }
        // lanes 0..7 finish this node: tx0, txout store, A-tile stage (+x stage on init)
        if (s == 0) {
            long long base = (long long)node * DD + q * 8;
            float val[8];
            if (t0h) {
                f16x8 t0v = *reinterpret_cast<const f16x8*>(t0h + base);
                #pragma unroll
                for (int i = 0; i < 8; ++i) val[i] = scale * acc[i] - (float)t0v[i];
            } else {
                #pragma unroll
                for (int i = 0; i < 8; ++i) val[i] = scale * acc[i];
            }
            f16x8 vh;
            #pragma unroll
            for (int i = 0; i < 8; ++i) vh[i] = (_Float16)val[i];
            if (txouth) *reinterpret_cast<f16x8*>(txouth + base) = vh;
            *reinterpret_cast<f16x8*>(&A_lds[nl * NPW + ni][q * 8]) = vh;
            if (W0) {
                f16x8 xv = h8[(long long)node * 8 + q];
                *reinterpret_cast<f16x8*>(&X_lds[nl * NPW + ni][q * 8]) = xv;
            }
        }
    }
    __syncthreads();

    // --- MFMA epilogue: D[16 nodes x 16 cols] for col-tile ct ---
    f32x4 d = {0.f, 0.f, 0.f, 0.f};
    f16x8 a0 = *reinterpret_cast<const f16x8*>(&A_lds[lr][lk * 8]);
    f16x8 a1 = *reinterpret_cast<const f16x8*>(&A_lds[lr][32 + lk * 8]);
    d = __builtin_amdgcn_mfma_f32_16x16x32_f16(a0, bfrag[0], d, 0, 0, 0);
    d = __builtin_amdgcn_mfma_f32_16x16x32_f16(a1, bfrag[1], d, 0, 0, 0);
    if (W0) {
        f16x8 x0 = *reinterpret_cast<const f16x8*>(&X_lds[lr][lk * 8]);
        f16x8 x1 = *reinterpret_cast<const f16x8*>(&X_lds[lr][32 + lk * 8]);
        d = __builtin_amdgcn_mfma_f32_16x16x32_f16(x0, bfrag0[0], d, 0, 0, 0);
        d = __builtin_amdgcn_mfma_f32_16x16x32_f16(x1, bfrag0[1], d, 0, 0, 0);
    }
    int nvb = min(NPB, N - blockIdx.x * NPB);
    int col = ct * 16 + lr;
    float bv = W0 ? bias[col] : 0.f;
    #pragma unroll
    for (int r = 0; r < 4; ++r) {
        int row = lk * 4 + r;
        if (row < nvb) {
            long long o = (long long)(blockIdx.x * NPB + row) * DD + col;
            out[o] = (W0 ? bv : out[o]) + d[r];
        }
    }
}

extern "C" void kernel_launch(void* const* d_in, const int* in_sizes, int n_in,
                              void* d_out, int out_size, void* d_ws, size_t ws_size,
                              hipStream_t stream) {
    const float* x  = (const float*)d_in[0];
    const int*   ei = (const int*)d_in[1];
    const float* W  = (const float*)d_in[2];
    const float* b  = (const float*)d_in[3];
    float* out = (float*)d_out;

    const int N = in_sizes[0] / DD;
    const int E = in_sizes[1] / 2;
    const int K = in_sizes[2] / (DD * DD);
    const long long ND = (long long)N * DD;

    const int* src = ei;
    const int* dst = ei + E;

    float*     ws    = (float*)d_ws;
    float*     dis   = ws;                          // N floats
    int*       degi  = (int*)(dis + N);             // N
    int*       cnt   = degi + N;                    // N
    int*       rowptr= cnt + N;                     // N+1
    int*       bsum  = rowptr + N + 1;              // 128
    int*       eoff  = bsum + 128;                  // E
    int2*      adj   = (int2*)(eoff + E);           // E int2 (8B aligned: offsets even)
    _Float16*  Xh    = (_Float16*)(adj + E);        // ND halves
    _Float16*  B1h   = Xh + ND;                     // ND
    _Float16*  B2h   = B1h + ND;                    // ND

    // zero degi + cnt (contiguous)
    (void)hipMemsetAsync(degi, 0, (size_t)(2 * N) * sizeof(int), stream);

    degcnt_kernel<<<(E / 4 + 255) / 256, 256, 0, stream>>>(src, dst, degi, cnt, eoff, E);
    dis_kernel<<<(N + 255) / 256, 256, 0, stream>>>(degi, dis, N);

    const long long n8 = ND / 8;
    cvt_kernel<<<(int)((n8 + 255) / 256), 256, 0, stream>>>(x, Xh, n8);

    const int nb = (N + 1023) / 1024;           // <= 128 required
    scan1_kernel<<<nb, 1024, 0, stream>>>(cnt, rowptr, bsum, N);
    scan2_kernel<<<1, 128, 0, stream>>>(bsum, nb);
    scan3_kernel<<<(N + 255) / 256, 256, 0, stream>>>(rowptr, bsum, N, E);
    fill_kernel<<<(E + 255) / 256, 256, 0, stream>>>(src, dst, dis, rowptr, eoff,
                                                     adj, E);

    const int pgrid = (N + NPB - 1) / NPB;

    // k=0 + k=1 fused: out = b + x@W0 + Tx1@W1 ; B1h = Tx1 = prop(x)
    prop_kernel<<<pgrid, 256, 0, stream>>>(rowptr, adj, Xh, nullptr,
                                           W + DD * DD, W, b,
                                           B1h, out, 1.0f, N);

    // k>=2: Txk = 2*prop(Tx1) - Tx0 ; out += Txk@Wk
    // Rotation: target always aliases next tx0 (own-index read-before-write);
    // never aliases the gather source.
    const _Float16* t0 = Xh;
    _Float16* t1 = B1h;
    _Float16* tg = B2h;
    for (int k = 2; k < K; ++k) {
        _Float16* txw = (k == K - 1) ? nullptr : tg;   // last Tx never read
        prop_kernel<<<pgrid, 256, 0, stream>>>(rowptr, adj, t1, t0,
                                               W + (long long)k * DD * DD, nullptr, b,
                                               txw, out, 2.0f, N);
        const _Float16* nt0 = t1;
        _Float16* nt1 = tg;
        tg = (_Float16*)nt0;
        t0 = nt0;
        t1 = nt1;
    }
}

// Round 12
// 536.985 us; speedup vs baseline: 1.6371x; 1.1776x over previous
//
#include <hip/hip_runtime.h>

#define DD 64
#define NPW 4    // nodes per wave (gather)
#define WPB 4    // waves per block
#define NPB 16   // nodes per block
#define ASTR 72  // halves per A_lds row (64 + 8 pad)
#define NBD 128  // histD partial-histogram blocks
#define NBS 64   // histS partial-histogram blocks

typedef int vint4 __attribute__((ext_vector_type(4)));
typedef _Float16 f16x8 __attribute__((ext_vector_type(8)));
typedef float f32x4 __attribute__((ext_vector_type(4)));

static __device__ __forceinline__ int rfl(int x) {
    return __builtin_amdgcn_readfirstlane(x);
}

// ---- histD: per-block LDS u8 histogram of dst + per-edge within-block rank ----
// 1 block/CU (100KB LDS). No global atomics.
__global__ __launch_bounds__(1024) void histD_kernel(
        const int* __restrict__ dst, unsigned char* __restrict__ dstp,
        unsigned char* __restrict__ ranks, int N, int NR, int E, int slice) {
    extern __shared__ unsigned int ldsH[];     // NR/4 words, u8 counters
    int nw = NR >> 2;
    int t = threadIdx.x;
    for (int i = t; i < nw; i += 1024) ldsH[i] = 0u;
    __syncthreads();
    int base = blockIdx.x * slice;
    int end = min(base + slice, E);
    for (int e = base + t; e < end; e += 1024) {
        int d = __builtin_nontemporal_load(dst + e);
        unsigned int sh = (unsigned int)(d & 3) * 8u;
        unsigned int old = atomicAdd(&ldsH[d >> 2], 1u << sh);
        unsigned char r = (unsigned char)((old >> sh) & 0xFFu);
        __builtin_nontemporal_store(r, ranks + e);
    }
    __syncthreads();
    unsigned int* outp = reinterpret_cast<unsigned int*>(dstp + (size_t)blockIdx.x * NR);
    for (int i = t; i < nw; i += 1024) outp[i] = ldsH[i];
}

// ---- histS: per-block LDS u8 histogram of src (no ranks needed) ----
__global__ __launch_bounds__(1024) void histS_kernel(
        const int* __restrict__ src, unsigned char* __restrict__ srcp,
        int N, int NR, int E, int slice) {
    extern __shared__ unsigned int ldsH[];
    int nw = NR >> 2;
    int t = threadIdx.x;
    for (int i = t; i < nw; i += 1024) ldsH[i] = 0u;
    __syncthreads();
    int base = blockIdx.x * slice;
    int end = min(base + slice, E);
    for (int e = base + t; e < end; e += 1024) {
        int s = __builtin_nontemporal_load(src + e);
        atomicAdd(&ldsH[s >> 2], 1u << ((unsigned int)(s & 3) * 8u));
    }
    __syncthreads();
    unsigned int* outp = reinterpret_cast<unsigned int*>(srcp + (size_t)blockIdx.x * NR);
    for (int i = t; i < nw; i += 1024) outp[i] = ldsH[i];
}

// ---- x -> fp16 ----
__global__ void cvt_kernel(const float* __restrict__ x, _Float16* __restrict__ xh,
                           long long n8) {
    long long i = (long long)blockIdx.x * blockDim.x + threadIdx.x;
    if (i < n8) {
        const float4* x4 = reinterpret_cast<const float4*>(x);
        float4 a = x4[i * 2], b = x4[i * 2 + 1];
        f16x8 h;
        h[0] = (_Float16)a.x; h[1] = (_Float16)a.y; h[2] = (_Float16)a.z; h[3] = (_Float16)a.w;
        h[4] = (_Float16)b.x; h[5] = (_Float16)b.y; h[6] = (_Float16)b.z; h[7] = (_Float16)b.w;
        reinterpret_cast<f16x8*>(xh)[i] = h;
    }
}

// ---- scan1: reduce partials (deg->dis; dstp count->exclusive block offsets),
//      then per-block exclusive scan of node counts ----
__global__ __launch_bounds__(1024) void scan1_kernel(
        unsigned char* dstp, const unsigned char* __restrict__ srcp,
        float* __restrict__ dis, int* __restrict__ rowptr,
        int* __restrict__ bsum, int N, int NR) {
    __shared__ int tmp[1024];
    int t = threadIdx.x;
    int g = blockIdx.x * 1024 + t;
    int c = 0;
    if (g < N) {
        int degv = 0;
        #pragma unroll 8
        for (int i = 0; i < NBS; ++i) degv += srcp[(size_t)i * NR + g];
        dis[g] = (degv > 0) ? rsqrtf((float)degv) : 0.0f;
        #pragma unroll 8
        for (int i = 0; i < NBD; ++i) {
            size_t idx = (size_t)i * NR + g;
            int v = dstp[idx];
            dstp[idx] = (unsigned char)c;    // exclusive prefix over blocks
            c += v;
        }
    }
    tmp[t] = c;
    __syncthreads();
    for (int off = 1; off < 1024; off <<= 1) {
        int a = (t >= off) ? tmp[t - off] : 0;
        __syncthreads();
        tmp[t] += a;
        __syncthreads();
    }
    if (g < N) rowptr[g] = tmp[t] - c;
    if (t == 1023) bsum[blockIdx.x] = tmp[1023];
}

__global__ __launch_bounds__(128) void scan2_kernel(int* __restrict__ data, int n) {
    __shared__ int tmp[128];
    int t = threadIdx.x;
    int v = (t < n) ? data[t] : 0;
    tmp[t] = v;
    __syncthreads();
    for (int off = 1; off < 128; off <<= 1) {
        int a = (t >= off) ? tmp[t - off] : 0;
        __syncthreads();
        tmp[t] += a;
        __syncthreads();
    }
    if (t < n) data[t] = tmp[t] - v;
}

__global__ void scan3_kernel(int* __restrict__ rowptr, const int* __restrict__ bsum,
                             int N, int E) {
    int g = blockIdx.x * blockDim.x + threadIdx.x;
    if (g < N) rowptr[g] += bsum[g >> 10];
    if (g == 0) rowptr[N] = E;
}

// ---- CSR fill (no atomics): pos = rowptr[d] + blockoff(dstp) + rank ----
__global__ void fill_kernel(const int* __restrict__ src, const int* __restrict__ dst,
                            const float* __restrict__ dis, const int* __restrict__ rowptr,
                            const unsigned char* __restrict__ dstp,
                            const unsigned char* __restrict__ ranks,
                            int2* __restrict__ adj, int E, int slice, int NR) {
    int e = blockIdx.x * blockDim.x + threadIdx.x;
    if (e < E) {
        int s = __builtin_nontemporal_load(src + e);
        int d = __builtin_nontemporal_load(dst + e);
        int i = e / slice;
        int rank = __builtin_nontemporal_load(ranks + e);
        int pos = rowptr[d] + (int)dstp[(size_t)i * NR + d] + rank;
        unsigned int wbits = (unsigned int)__float_as_int(-dis[s] * dis[d]);
        unsigned long long packed = (unsigned long long)(unsigned int)s |
                                    ((unsigned long long)wbits << 32);
        __builtin_nontemporal_store(packed,
            reinterpret_cast<unsigned long long*>(adj + pos));
    }
}

// ---- prop: v = scale*gather(h) - tx0 ; txout = fp16(v) ; out (+)= v@Wk [+ x@W0 + b] ----
// Gather: 8 edge-slots x 8 lanes x half8, 2-deep adj prefetch, butterfly reduce.
// Epilogue: MFMA (16 node-rows staged in padded LDS; wave = one 16x16 col-tile).
// NOTE: txouth may alias t0h (own-index read-before-write) — no __restrict__ there.
__global__ __launch_bounds__(256, 8) void prop_kernel(
        const int* __restrict__ rowptr, const int2* __restrict__ adj,
        const _Float16* __restrict__ h, const _Float16* t0h,
        const float* __restrict__ Wk, const float* __restrict__ W0,
        const float* __restrict__ bias,
        _Float16* txouth, float* out, float scale, int N) {
    __shared__ _Float16 A_lds[NPB][ASTR];
    __shared__ _Float16 X_lds[NPB][ASTR];   // used on init (W0) pass only
    int t = threadIdx.x;
    int nl = t >> 6, lane = t & 63;
    int ct = nl;               // this wave's output col-tile
    int lr = lane & 15;        // frag m/n index
    int lk = lane >> 4;        // frag k-group

    f16x8 bfrag[2], bfrag0[2];
    #pragma unroll
    for (int kt = 0; kt < 2; ++kt) {
        #pragma unroll
        for (int i = 0; i < 8; ++i) {
            int r = kt * 32 + lk * 8 + i;
            bfrag[kt][i] = (_Float16)Wk[r * DD + ct * 16 + lr];
        }
    }
    if (W0) {
        #pragma unroll
        for (int kt = 0; kt < 2; ++kt) {
            #pragma unroll
            for (int i = 0; i < 8; ++i) {
                int r = kt * 32 + lk * 8 + i;
                bfrag0[kt][i] = (_Float16)W0[r * DD + ct * 16 + lr];
            }
        }
    }

    int s = lane >> 3;         // edge slot 0..7
    int q = lane & 7;          // half8 chunk: columns 8q..8q+7
    int node0 = blockIdx.x * NPB + nl * NPW;
    int nv = min(NPW, max(0, N - node0));
    const f16x8* h8 = reinterpret_cast<const f16x8*>(h);

    for (int ni = 0; ni < nv; ++ni) {
        int node = node0 + ni;
        int beg = rfl(rowptr[node]);
        int end = rfl(rowptr[node + 1]);
        float acc[8];
        #pragma unroll
        for (int i = 0; i < 8; ++i) acc[i] = 0.f;
        int j = beg + s;
        int2 e0 = (j < end) ? adj[j] : make_int2(0, 0);
        int2 e1 = (j + 8 < end) ? adj[j + 8] : make_int2(0, 0);
        while (j < end) {
            int jn = j + 16;
            int2 n0 = (jn < end) ? adj[jn] : make_int2(0, 0);
            int2 n1 = (jn + 8 < end) ? adj[jn + 8] : make_int2(0, 0);
            f16x8 g0 = h8[(long long)e0.x * 8 + q];
            f16x8 g1 = h8[(long long)e1.x * 8 + q];
            float w0 = __int_as_float(e0.y), w1 = __int_as_float(e1.y);
            #pragma unroll
            for (int i = 0; i < 8; ++i)
                acc[i] += w0 * (float)g0[i] + w1 * (float)g1[i];
            e0 = n0; e1 = n1; j = jn;
        }
        #pragma unroll
        for (int m = 8; m < 64; m <<= 1) {
            #pragma unroll
            for (int i = 0; i < 8; ++i) acc[i] += __shfl_xor(acc[i], m, 64);
        }
        if (s == 0) {
            long long base = (long long)node * DD + q * 8;
            float val[8];
            if (t0h) {
                f16x8 t0v = *reinterpret_cast<const f16x8*>(t0h + base);
                #pragma unroll
                for (int i = 0; i < 8; ++i) val[i] = scale * acc[i] - (float)t0v[i];
            } else {
                #pragma unroll
                for (int i = 0; i < 8; ++i) val[i] = scale * acc[i];
            }
            f16x8 vh;
            #pragma unroll
            for (int i = 0; i < 8; ++i) vh[i] = (_Float16)val[i];
            if (txouth) *reinterpret_cast<f16x8*>(txouth + base) = vh;
            *reinterpret_cast<f16x8*>(&A_lds[nl * NPW + ni][q * 8]) = vh;
            if (W0) {
                f16x8 xv = h8[(long long)node * 8 + q];
                *reinterpret_cast<f16x8*>(&X_lds[nl * NPW + ni][q * 8]) = xv;
            }
        }
    }
    __syncthreads();

    f32x4 d = {0.f, 0.f, 0.f, 0.f};
    f16x8 a0 = *reinterpret_cast<const f16x8*>(&A_lds[lr][lk * 8]);
    f16x8 a1 = *reinterpret_cast<const f16x8*>(&A_lds[lr][32 + lk * 8]);
    d = __builtin_amdgcn_mfma_f32_16x16x32_f16(a0, bfrag[0], d, 0, 0, 0);
    d = __builtin_amdgcn_mfma_f32_16x16x32_f16(a1, bfrag[1], d, 0, 0, 0);
    if (W0) {
        f16x8 x0 = *reinterpret_cast<const f16x8*>(&X_lds[lr][lk * 8]);
        f16x8 x1 = *reinterpret_cast<const f16x8*>(&X_lds[lr][32 + lk * 8]);
        d = __builtin_amdgcn_mfma_f32_16x16x32_f16(x0, bfrag0[0], d, 0, 0, 0);
        d = __builtin_amdgcn_mfma_f32_16x16x32_f16(x1, bfrag0[1], d, 0, 0, 0);
    }
    int nvb = min(NPB, N - blockIdx.x * NPB);
    int col = ct * 16 + lr;
    float bv = W0 ? bias[col] : 0.f;
    #pragma unroll
    for (int r = 0; r < 4; ++r) {
        int row = lk * 4 + r;
        if (row < nvb) {
            long long o = (long long)(blockIdx.x * NPB + row) * DD + col;
            out[o] = (W0 ? bv : out[o]) + d[r];
        }
    }
}

extern "C" void kernel_launch(void* const* d_in, const int* in_sizes, int n_in,
                              void* d_out, int out_size, void* d_ws, size_t ws_size,
                              hipStream_t stream) {
    const float* x  = (const float*)d_in[0];
    const int*   ei = (const int*)d_in[1];
    const float* W  = (const float*)d_in[2];
    const float* b  = (const float*)d_in[3];
    float* out = (float*)d_out;

    const int N = in_sizes[0] / DD;
    const int E = in_sizes[1] / 2;
    const int K = in_sizes[2] / (DD * DD);
    const long long ND = (long long)N * DD;
    const int NR = ((N + 3) / 4) * 4;           // u8 partial row stride

    const int* src = ei;
    const int* dst = ei + E;

    char* wp = (char*)d_ws;
    float* dis = (float*)wp;                    wp += (size_t)N * 4;
    int* rowptr = (int*)wp;                     wp += (size_t)(N + 1) * 4;
    int* bsum = (int*)wp;                       wp += 128 * 4;
    unsigned char* dstp = (unsigned char*)wp;   wp += (size_t)NBD * NR;
    unsigned char* srcp = (unsigned char*)wp;   wp += (size_t)NBS * NR;
    unsigned char* ranks = (unsigned char*)wp;  wp += ((size_t)E + 15) & ~(size_t)15;
    int2* adj = (int2*)wp;                      wp += (size_t)E * 8;
    _Float16* Xh = (_Float16*)wp;               wp += (size_t)ND * 2;
    _Float16* B1h = (_Float16*)wp;              wp += (size_t)ND * 2;

    const int sliceD = (E + NBD - 1) / NBD;
    const int sliceS = (E + NBS - 1) / NBS;
    const size_t ldsH = (size_t)NR;             // u8 counters

    histD_kernel<<<NBD, 1024, ldsH, stream>>>(dst, dstp, ranks, N, NR, E, sliceD);
    histS_kernel<<<NBS, 1024, ldsH, stream>>>(src, srcp, N, NR, E, sliceS);

    const long long n8 = ND / 8;
    cvt_kernel<<<(int)((n8 + 255) / 256), 256, 0, stream>>>(x, Xh, n8);

    const int nb = (N + 1023) / 1024;           // <= 128 required
    scan1_kernel<<<nb, 1024, 0, stream>>>(dstp, srcp, dis, rowptr, bsum, N, NR);
    scan2_kernel<<<1, 128, 0, stream>>>(bsum, nb);
    scan3_kernel<<<(N + 255) / 256, 256, 0, stream>>>(rowptr, bsum, N, E);
    fill_kernel<<<(E + 255) / 256, 256, 0, stream>>>(src, dst, dis, rowptr, dstp,
                                                     ranks, adj, E, sliceD, NR);

    const int pgrid = (N + NPB - 1) / NPB;

    // k=0 + k=1 fused: out = b + x@W0 + Tx1@W1 ; B1h = Tx1 = prop(x)
    prop_kernel<<<pgrid, 256, 0, stream>>>(rowptr, adj, Xh, nullptr,
                                           W + DD * DD, W, b,
                                           B1h, out, 1.0f, N);

    // k>=2: Txk = 2*prop(Tx1) - Tx0 ; out += Txk@Wk
    // Two-buffer rotation: target aliases tx0 (own-index read-before-write,
    // same-thread ordered); target never aliases the gather source h.
    const _Float16* hbuf = B1h;
    _Float16* t0buf = Xh;
    for (int k = 2; k < K; ++k) {
        _Float16* txw = (k == K - 1) ? nullptr : t0buf;   // last Tx never read
        prop_kernel<<<pgrid, 256, 0, stream>>>(rowptr, adj, hbuf, t0buf,
                                               W + (long long)k * DD * DD, nullptr, b,
                                               txw, out, 2.0f, N);
        _Float16* nh = t0buf;            // Tx_k lives where tx0 was
        t0buf = (_Float16*)hbuf;         // Tx_{k-1} becomes next tx0
        hbuf = nh;
    }
}

// Round 13
// 483.809 us; speedup vs baseline: 1.8171x; 1.1099x over previous
//
#include <hip/hip_runtime.h>

#define DD 64
#define NPW 4    // nodes per wave (gather)
#define WPB 4    // waves per block
#define NPB 16   // nodes per block
#define ASTR 72  // halves per A_lds row (64 + 8 pad)
#define NBD 128  // histD partial-histogram blocks
#define NBS 64   // histS partial-histogram blocks

typedef int vint4 __attribute__((ext_vector_type(4)));
typedef _Float16 f16x8 __attribute__((ext_vector_type(8)));
typedef float f32x4 __attribute__((ext_vector_type(4)));
typedef unsigned long long u64;

static __device__ __forceinline__ int rfl(int x) {
    return __builtin_amdgcn_readfirstlane(x);
}

// ---- histD: per-block LDS u8 histogram of dst + per-edge within-block rank ----
__global__ __launch_bounds__(1024) void histD_kernel(
        const int* __restrict__ dst, unsigned char* __restrict__ dstp,
        unsigned char* __restrict__ ranks, int N, int NR, int E, int slice) {
    extern __shared__ unsigned int ldsH[];
    int nw = NR >> 2;
    int t = threadIdx.x;
    for (int i = t; i < nw; i += 1024) ldsH[i] = 0u;
    __syncthreads();
    int base = blockIdx.x * slice;
    int end = min(base + slice, E);
    for (int e = base + t; e < end; e += 1024) {
        int d = __builtin_nontemporal_load(dst + e);
        unsigned int sh = (unsigned int)(d & 3) * 8u;
        unsigned int old = atomicAdd(&ldsH[d >> 2], 1u << sh);
        unsigned char r = (unsigned char)((old >> sh) & 0xFFu);
        __builtin_nontemporal_store(r, ranks + e);
    }
    __syncthreads();
    unsigned int* outp = reinterpret_cast<unsigned int*>(dstp + (size_t)blockIdx.x * NR);
    for (int i = t; i < nw; i += 1024) outp[i] = ldsH[i];
}

// ---- histS: per-block LDS u8 histogram of src ----
__global__ __launch_bounds__(1024) void histS_kernel(
        const int* __restrict__ src, unsigned char* __restrict__ srcp,
        int N, int NR, int E, int slice) {
    extern __shared__ unsigned int ldsH[];
    int nw = NR >> 2;
    int t = threadIdx.x;
    for (int i = t; i < nw; i += 1024) ldsH[i] = 0u;
    __syncthreads();
    int base = blockIdx.x * slice;
    int end = min(base + slice, E);
    for (int e = base + t; e < end; e += 1024) {
        int s = __builtin_nontemporal_load(src + e);
        atomicAdd(&ldsH[s >> 2], 1u << ((unsigned int)(s & 3) * 8u));
    }
    __syncthreads();
    unsigned int* outp = reinterpret_cast<unsigned int*>(srcp + (size_t)blockIdx.x * NR);
    for (int i = t; i < nw; i += 1024) outp[i] = ldsH[i];
}

// ---- x -> fp16 ----
__global__ void cvt_kernel(const float* __restrict__ x, _Float16* __restrict__ xh,
                           long long n8) {
    long long i = (long long)blockIdx.x * blockDim.x + threadIdx.x;
    if (i < n8) {
        const float4* x4 = reinterpret_cast<const float4*>(x);
        float4 a = x4[i * 2], b = x4[i * 2 + 1];
        f16x8 h;
        h[0] = (_Float16)a.x; h[1] = (_Float16)a.y; h[2] = (_Float16)a.z; h[3] = (_Float16)a.w;
        h[4] = (_Float16)b.x; h[5] = (_Float16)b.y; h[6] = (_Float16)b.z; h[7] = (_Float16)b.w;
        reinterpret_cast<f16x8*>(xh)[i] = h;
    }
}

// ---- scan1: reduce partials; per-block exclusive scan ----
__global__ __launch_bounds__(1024) void scan1_kernel(
        unsigned char* dstp, const unsigned char* __restrict__ srcp,
        float* __restrict__ dis, int* __restrict__ rowptr,
        int* __restrict__ bsum, int N, int NR) {
    __shared__ int tmp[1024];
    int t = threadIdx.x;
    int g = blockIdx.x * 1024 + t;
    int c = 0;
    if (g < N) {
        int degv = 0;
        #pragma unroll 8
        for (int i = 0; i < NBS; ++i) degv += srcp[(size_t)i * NR + g];
        dis[g] = (degv > 0) ? rsqrtf((float)degv) : 0.0f;
        #pragma unroll 8
        for (int i = 0; i < NBD; ++i) {
            size_t idx = (size_t)i * NR + g;
            int v = dstp[idx];
            dstp[idx] = (unsigned char)c;
            c += v;
        }
    }
    tmp[t] = c;
    __syncthreads();
    for (int off = 1; off < 1024; off <<= 1) {
        int a = (t >= off) ? tmp[t - off] : 0;
        __syncthreads();
        tmp[t] += a;
        __syncthreads();
    }
    if (g < N) rowptr[g] = tmp[t] - c;
    if (t == 1023) bsum[blockIdx.x] = tmp[1023];
}

__global__ __launch_bounds__(128) void scan2_kernel(int* __restrict__ data, int n) {
    __shared__ int tmp[128];
    int t = threadIdx.x;
    int v = (t < n) ? data[t] : 0;
    tmp[t] = v;
    __syncthreads();
    for (int off = 1; off < 128; off <<= 1) {
        int a = (t >= off) ? tmp[t - off] : 0;
        __syncthreads();
        tmp[t] += a;
        __syncthreads();
    }
    if (t < n) data[t] = tmp[t] - v;
}

__global__ void scan3_kernel(int* __restrict__ rowptr, const int* __restrict__ bsum,
                             int N, int E) {
    int g = blockIdx.x * blockDim.x + threadIdx.x;
    if (g < N) rowptr[g] += bsum[g >> 10];
    if (g == 0) rowptr[N] = E;
}

// ---- CSR fill (no atomics) ----
__global__ void fill_kernel(const int* __restrict__ src, const int* __restrict__ dst,
                            const float* __restrict__ dis, const int* __restrict__ rowptr,
                            const unsigned char* __restrict__ dstp,
                            const unsigned char* __restrict__ ranks,
                            int2* __restrict__ adj, int E, int slice, int NR) {
    int e = blockIdx.x * blockDim.x + threadIdx.x;
    if (e < E) {
        int s = __builtin_nontemporal_load(src + e);
        int d = __builtin_nontemporal_load(dst + e);
        int i = e / slice;
        int rank = __builtin_nontemporal_load(ranks + e);
        int pos = rowptr[d] + (int)dstp[(size_t)i * NR + d] + rank;
        unsigned int wbits = (unsigned int)__float_as_int(-dis[s] * dis[d]);
        u64 packed = (u64)(unsigned int)s | ((u64)wbits << 32);
        __builtin_nontemporal_store(packed, reinterpret_cast<u64*>(adj + pos));
    }
}

// ---- shared gather: acc[8] = sum_e w_e * h[src_e][8q..8q+7], butterfly-reduced ----
// After return, lanes with s==0 hold the full row sums for chunk q.
static __device__ __forceinline__ void gather_row(
        const int* __restrict__ rowptr, const int2* __restrict__ adj,
        const f16x8* __restrict__ h8, int node, int s, int q, float* acc) {
    int beg = rfl(rowptr[node]);
    int end = rfl(rowptr[node + 1]);
    #pragma unroll
    for (int i = 0; i < 8; ++i) acc[i] = 0.f;
    int j = beg + s;
    const u64* adj8 = reinterpret_cast<const u64*>(adj);
    u64 e0 = (j < end) ? __builtin_nontemporal_load(adj8 + j) : 0ull;
    u64 e1 = (j + 8 < end) ? __builtin_nontemporal_load(adj8 + j + 8) : 0ull;
    while (j < end) {
        int jn = j + 16;
        u64 n0 = (jn < end) ? __builtin_nontemporal_load(adj8 + jn) : 0ull;
        u64 n1 = (jn + 8 < end) ? __builtin_nontemporal_load(adj8 + jn + 8) : 0ull;
        f16x8 g0 = h8[(long long)(int)(unsigned int)e0 * 8 + q];
        f16x8 g1 = h8[(long long)(int)(unsigned int)e1 * 8 + q];
        float w0 = __int_as_float((int)(e0 >> 32));
        float w1 = __int_as_float((int)(e1 >> 32));
        #pragma unroll
        for (int i = 0; i < 8; ++i)
            acc[i] += w0 * (float)g0[i] + w1 * (float)g1[i];
        e0 = n0; e1 = n1; j = jn;
    }
    #pragma unroll
    for (int m = 8; m < 64; m <<= 1) {
        #pragma unroll
        for (int i = 0; i < 8; ++i) acc[i] += __shfl_xor(acc[i], m, 64);
    }
}

// ---- prop_first: Tx1 = gather(x) ; tx1out = fp16(Tx1) ; out = b + x@W0 + Tx1@W1 ----
__global__ __launch_bounds__(256, 8) void prop_first_kernel(
        const int* __restrict__ rowptr, const int2* __restrict__ adj,
        const _Float16* __restrict__ xh,
        const float* __restrict__ W0, const float* __restrict__ W1,
        const float* __restrict__ bias,
        _Float16* __restrict__ tx1out, float* __restrict__ out, int N) {
    __shared__ _Float16 A_lds[NPB][ASTR];
    __shared__ _Float16 X_lds[NPB][ASTR];
    int t = threadIdx.x;
    int nl = t >> 6, lane = t & 63;
    int ct = nl, lr = lane & 15, lk = lane >> 4;

    f16x8 bf1[2], bf0[2];
    #pragma unroll
    for (int kt = 0; kt < 2; ++kt)
        #pragma unroll
        for (int i = 0; i < 8; ++i) {
            int r = kt * 32 + lk * 8 + i;
            bf1[kt][i] = (_Float16)W1[r * DD + ct * 16 + lr];
            bf0[kt][i] = (_Float16)W0[r * DD + ct * 16 + lr];
        }

    int s = lane >> 3, q = lane & 7;
    int node0 = blockIdx.x * NPB + nl * NPW;
    int nv = min(NPW, max(0, N - node0));
    const f16x8* h8 = reinterpret_cast<const f16x8*>(xh);

    for (int ni = 0; ni < nv; ++ni) {
        int node = node0 + ni;
        float acc[8];
        gather_row(rowptr, adj, h8, node, s, q, acc);
        if (s == 0) {
            long long base = (long long)node * DD + q * 8;
            f16x8 vh;
            #pragma unroll
            for (int i = 0; i < 8; ++i) vh[i] = (_Float16)acc[i];
            __builtin_nontemporal_store(vh, reinterpret_cast<f16x8*>(tx1out + base));
            *reinterpret_cast<f16x8*>(&A_lds[nl * NPW + ni][q * 8]) = vh;
            *reinterpret_cast<f16x8*>(&X_lds[nl * NPW + ni][q * 8]) =
                h8[(long long)node * 8 + q];
        }
    }
    __syncthreads();

    f32x4 d = {0.f, 0.f, 0.f, 0.f};
    f16x8 a0 = *reinterpret_cast<const f16x8*>(&A_lds[lr][lk * 8]);
    f16x8 a1 = *reinterpret_cast<const f16x8*>(&A_lds[lr][32 + lk * 8]);
    f16x8 x0 = *reinterpret_cast<const f16x8*>(&X_lds[lr][lk * 8]);
    f16x8 x1 = *reinterpret_cast<const f16x8*>(&X_lds[lr][32 + lk * 8]);
    d = __builtin_amdgcn_mfma_f32_16x16x32_f16(a0, bf1[0], d, 0, 0, 0);
    d = __builtin_amdgcn_mfma_f32_16x16x32_f16(a1, bf1[1], d, 0, 0, 0);
    d = __builtin_amdgcn_mfma_f32_16x16x32_f16(x0, bf0[0], d, 0, 0, 0);
    d = __builtin_amdgcn_mfma_f32_16x16x32_f16(x1, bf0[1], d, 0, 0, 0);
    int nvb = min(NPB, N - blockIdx.x * NPB);
    int col = ct * 16 + lr;
    float bv = bias[col];
    #pragma unroll
    for (int r = 0; r < 4; ++r) {
        int row = lk * 4 + r;
        if (row < nvb) {
            long long o = (long long)(blockIdx.x * NPB + row) * DD + col;
            __builtin_nontemporal_store(bv + d[r], out + o);
        }
    }
}

// ---- prop_mid: txout = fp16(2*gather(h) - t0) ; no GEMM, no out ----
// txout aliases t0 (own-index read-before-write) — no __restrict__ on those.
__global__ __launch_bounds__(256, 8) void prop_mid_kernel(
        const int* __restrict__ rowptr, const int2* __restrict__ adj,
        const _Float16* __restrict__ h, const _Float16* t0h,
        _Float16* txouth, int N) {
    int t = threadIdx.x;
    int nl = t >> 6, lane = t & 63;
    int s = lane >> 3, q = lane & 7;
    int node0 = blockIdx.x * NPB + nl * NPW;
    int nv = min(NPW, max(0, N - node0));
    const f16x8* h8 = reinterpret_cast<const f16x8*>(h);

    for (int ni = 0; ni < nv; ++ni) {
        int node = node0 + ni;
        float acc[8];
        gather_row(rowptr, adj, h8, node, s, q, acc);
        if (s == 0) {
            long long base = (long long)node * DD + q * 8;
            f16x8 t0v = __builtin_nontemporal_load(
                reinterpret_cast<const f16x8*>(t0h + base));
            f16x8 vh;
            #pragma unroll
            for (int i = 0; i < 8; ++i)
                vh[i] = (_Float16)(2.0f * acc[i] - (float)t0v[i]);
            __builtin_nontemporal_store(vh, reinterpret_cast<f16x8*>(txouth + base));
        }
    }
}

// ---- prop_last: Tx4 = 2*gather(Tx3) - Tx2 ; out += Tx2@W2 + Tx3@W3 + Tx4@W4 ----
__global__ __launch_bounds__(256, 6) void prop_last_kernel(
        const int* __restrict__ rowptr, const int2* __restrict__ adj,
        const _Float16* __restrict__ h /*Tx3*/, const _Float16* __restrict__ t0h /*Tx2*/,
        const float* __restrict__ W2, const float* __restrict__ W3,
        const float* __restrict__ W4, float* __restrict__ out, int N) {
    __shared__ _Float16 A_lds[NPB][ASTR];    // Tx4
    __shared__ _Float16 T2_lds[NPB][ASTR];
    __shared__ _Float16 T3_lds[NPB][ASTR];
    int t = threadIdx.x;
    int nl = t >> 6, lane = t & 63;
    int ct = nl, lr = lane & 15, lk = lane >> 4;

    f16x8 bf2[2], bf3[2], bf4[2];
    #pragma unroll
    for (int kt = 0; kt < 2; ++kt)
        #pragma unroll
        for (int i = 0; i < 8; ++i) {
            int r = kt * 32 + lk * 8 + i;
            bf2[kt][i] = (_Float16)W2[r * DD + ct * 16 + lr];
            bf3[kt][i] = (_Float16)W3[r * DD + ct * 16 + lr];
            bf4[kt][i] = (_Float16)W4[r * DD + ct * 16 + lr];
        }

    int s = lane >> 3, q = lane & 7;
    int node0 = blockIdx.x * NPB + nl * NPW;
    int nv = min(NPW, max(0, N - node0));
    const f16x8* h8 = reinterpret_cast<const f16x8*>(h);

    for (int ni = 0; ni < nv; ++ni) {
        int node = node0 + ni;
        float acc[8];
        gather_row(rowptr, adj, h8, node, s, q, acc);
        if (s == 0) {
            long long base = (long long)node * DD + q * 8;
            f16x8 t0v = __builtin_nontemporal_load(
                reinterpret_cast<const f16x8*>(t0h + base));
            f16x8 vh;
            #pragma unroll
            for (int i = 0; i < 8; ++i)
                vh[i] = (_Float16)(2.0f * acc[i] - (float)t0v[i]);
            int rowi = nl * NPW + ni;
            *reinterpret_cast<f16x8*>(&A_lds[rowi][q * 8]) = vh;
            *reinterpret_cast<f16x8*>(&T2_lds[rowi][q * 8]) = t0v;
            *reinterpret_cast<f16x8*>(&T3_lds[rowi][q * 8]) =
                h8[(long long)node * 8 + q];
        }
    }
    __syncthreads();

    f32x4 d = {0.f, 0.f, 0.f, 0.f};
    #pragma unroll
    for (int kt = 0; kt < 2; ++kt) {
        f16x8 a4 = *reinterpret_cast<const f16x8*>(&A_lds[lr][kt * 32 + lk * 8]);
        f16x8 a2 = *reinterpret_cast<const f16x8*>(&T2_lds[lr][kt * 32 + lk * 8]);
        f16x8 a3 = *reinterpret_cast<const f16x8*>(&T3_lds[lr][kt * 32 + lk * 8]);
        d = __builtin_amdgcn_mfma_f32_16x16x32_f16(a4, bf4[kt], d, 0, 0, 0);
        d = __builtin_amdgcn_mfma_f32_16x16x32_f16(a2, bf2[kt], d, 0, 0, 0);
        d = __builtin_amdgcn_mfma_f32_16x16x32_f16(a3, bf3[kt], d, 0, 0, 0);
    }
    int nvb = min(NPB, N - blockIdx.x * NPB);
    int col = ct * 16 + lr;
    #pragma unroll
    for (int r = 0; r < 4; ++r) {
        int row = lk * 4 + r;
        if (row < nvb) {
            long long o = (long long)(blockIdx.x * NPB + row) * DD + col;
            float oldv = __builtin_nontemporal_load(out + o);
            __builtin_nontemporal_store(oldv + d[r], out + o);
        }
    }
}

// ---- generic prop (fallback for K != 5): as round 12 ----
__global__ __launch_bounds__(256, 8) void prop_kernel(
        const int* __restrict__ rowptr, const int2* __restrict__ adj,
        const _Float16* __restrict__ h, const _Float16* t0h,
        const float* __restrict__ Wk, const float* __restrict__ W0,
        const float* __restrict__ bias,
        _Float16* txouth, float* out, float scale, int N) {
    __shared__ _Float16 A_lds[NPB][ASTR];
    __shared__ _Float16 X_lds[NPB][ASTR];
    int t = threadIdx.x;
    int nl = t >> 6, lane = t & 63;
    int ct = nl, lr = lane & 15, lk = lane >> 4;

    f16x8 bfrag[2], bfrag0[2];
    #pragma unroll
    for (int kt = 0; kt < 2; ++kt)
        #pragma unroll
        for (int i = 0; i < 8; ++i) {
            int r = kt * 32 + lk * 8 + i;
            bfrag[kt][i] = (_Float16)Wk[r * DD + ct * 16 + lr];
        }
    if (W0) {
        #pragma unroll
        for (int kt = 0; kt < 2; ++kt)
            #pragma unroll
            for (int i = 0; i < 8; ++i) {
                int r = kt * 32 + lk * 8 + i;
                bfrag0[kt][i] = (_Float16)W0[r * DD + ct * 16 + lr];
            }
    }

    int s = lane >> 3, q = lane & 7;
    int node0 = blockIdx.x * NPB + nl * NPW;
    int nv = min(NPW, max(0, N - node0));
    const f16x8* h8 = reinterpret_cast<const f16x8*>(h);

    for (int ni = 0; ni < nv; ++ni) {
        int node = node0 + ni;
        float acc[8];
        gather_row(rowptr, adj, h8, node, s, q, acc);
        if (s == 0) {
            long long base = (long long)node * DD + q * 8;
            float val[8];
            if (t0h) {
                f16x8 t0v = *reinterpret_cast<const f16x8*>(t0h + base);
                #pragma unroll
                for (int i = 0; i < 8; ++i) val[i] = scale * acc[i] - (float)t0v[i];
            } else {
                #pragma unroll
                for (int i = 0; i < 8; ++i) val[i] = scale * acc[i];
            }
            f16x8 vh;
            #pragma unroll
            for (int i = 0; i < 8; ++i) vh[i] = (_Float16)val[i];
            if (txouth) *reinterpret_cast<f16x8*>(txouth + base) = vh;
            *reinterpret_cast<f16x8*>(&A_lds[nl * NPW + ni][q * 8]) = vh;
            if (W0)
                *reinterpret_cast<f16x8*>(&X_lds[nl * NPW + ni][q * 8]) =
                    h8[(long long)node * 8 + q];
        }
    }
    __syncthreads();

    f32x4 d = {0.f, 0.f, 0.f, 0.f};
    f16x8 a0 = *reinterpret_cast<const f16x8*>(&A_lds[lr][lk * 8]);
    f16x8 a1 = *reinterpret_cast<const f16x8*>(&A_lds[lr][32 + lk * 8]);
    d = __builtin_amdgcn_mfma_f32_16x16x32_f16(a0, bfrag[0], d, 0, 0, 0);
    d = __builtin_amdgcn_mfma_f32_16x16x32_f16(a1, bfrag[1], d, 0, 0, 0);
    if (W0) {
        f16x8 x0 = *reinterpret_cast<const f16x8*>(&X_lds[lr][lk * 8]);
        f16x8 x1 = *reinterpret_cast<const f16x8*>(&X_lds[lr][32 + lk * 8]);
        d = __builtin_amdgcn_mfma_f32_16x16x32_f16(x0, bfrag0[0], d, 0, 0, 0);
        d = __builtin_amdgcn_mfma_f32_16x16x32_f16(x1, bfrag0[1], d, 0, 0, 0);
    }
    int nvb = min(NPB, N - blockIdx.x * NPB);
    int col = ct * 16 + lr;
    float bv = W0 ? bias[col] : 0.f;
    #pragma unroll
    for (int r = 0; r < 4; ++r) {
        int row = lk * 4 + r;
        if (row < nvb) {
            long long o = (long long)(blockIdx.x * NPB + row) * DD + col;
            out[o] = (W0 ? bv : out[o]) + d[r];
        }
    }
}

extern "C" void kernel_launch(void* const* d_in, const int* in_sizes, int n_in,
                              void* d_out, int out_size, void* d_ws, size_t ws_size,
                              hipStream_t stream) {
    const float* x  = (const float*)d_in[0];
    const int*   ei = (const int*)d_in[1];
    const float* W  = (const float*)d_in[2];
    const float* b  = (const float*)d_in[3];
    float* out = (float*)d_out;

    const int N = in_sizes[0] / DD;
    const int E = in_sizes[1] / 2;
    const int K = in_sizes[2] / (DD * DD);
    const long long ND = (long long)N * DD;
    const int NR = ((N + 3) / 4) * 4;

    const int* src = ei;
    const int* dst = ei + E;

    char* wp = (char*)d_ws;
    float* dis = (float*)wp;                    wp += (size_t)N * 4;
    int* rowptr = (int*)wp;                     wp += (size_t)(N + 1) * 4;
    int* bsum = (int*)wp;                       wp += 128 * 4;
    unsigned char* dstp = (unsigned char*)wp;   wp += (size_t)NBD * NR;
    unsigned char* srcp = (unsigned char*)wp;   wp += (size_t)NBS * NR;
    unsigned char* ranks = (unsigned char*)wp;  wp += ((size_t)E + 15) & ~(size_t)15;
    int2* adj = (int2*)wp;                      wp += (size_t)E * 8;
    _Float16* Xh = (_Float16*)wp;               wp += (size_t)ND * 2;
    _Float16* B1h = (_Float16*)wp;              wp += (size_t)ND * 2;

    const int sliceD = (E + NBD - 1) / NBD;
    const int sliceS = (E + NBS - 1) / NBS;
    const size_t ldsH = (size_t)NR;

    histD_kernel<<<NBD, 1024, ldsH, stream>>>(dst, dstp, ranks, N, NR, E, sliceD);
    histS_kernel<<<NBS, 1024, ldsH, stream>>>(src, srcp, N, NR, E, sliceS);

    const long long n8 = ND / 8;
    cvt_kernel<<<(int)((n8 + 255) / 256), 256, 0, stream>>>(x, Xh, n8);

    const int nb = (N + 1023) / 1024;
    scan1_kernel<<<nb, 1024, 0, stream>>>(dstp, srcp, dis, rowptr, bsum, N, NR);
    scan2_kernel<<<1, 128, 0, stream>>>(bsum, nb);
    scan3_kernel<<<(N + 255) / 256, 256, 0, stream>>>(rowptr, bsum, N, E);
    fill_kernel<<<(E + 255) / 256, 256, 0, stream>>>(src, dst, dis, rowptr, dstp,
                                                     ranks, adj, E, sliceD, NR);

    const int pgrid = (N + NPB - 1) / NPB;
    const int W1sz = DD * DD;

    if (K == 5) {
        // out = b + x@W0 + Tx1@W1 ; B1h = Tx1
        prop_first_kernel<<<pgrid, 256, 0, stream>>>(rowptr, adj, Xh,
                                                     W, W + W1sz, b, B1h, out, N);
        // Tx2 = 2*prop(Tx1) - x      -> Xh   (txout aliases t0, safe)
        prop_mid_kernel<<<pgrid, 256, 0, stream>>>(rowptr, adj, B1h, Xh, Xh, N);
        // Tx3 = 2*prop(Tx2) - Tx1    -> B1h
        prop_mid_kernel<<<pgrid, 256, 0, stream>>>(rowptr, adj, Xh, B1h, B1h, N);
        // Tx4 = 2*prop(Tx3) - Tx2 ; out += Tx2@W2 + Tx3@W3 + Tx4@W4
        prop_last_kernel<<<pgrid, 256, 0, stream>>>(rowptr, adj, B1h, Xh,
                                                    W + 2 * W1sz, W + 3 * W1sz,
                                                    W + 4 * W1sz, out, N);
    } else {
        // generic fallback (round-12 path)
        prop_kernel<<<pgrid, 256, 0, stream>>>(rowptr, adj, Xh, nullptr,
                                               W + W1sz, W, b, B1h, out, 1.0f, N);
        const _Float16* hbuf = B1h;
        _Float16* t0buf = Xh;
        for (int k = 2; k < K; ++k) {
            _Float16* txw = (k == K - 1) ? nullptr : t0buf;
            prop_kernel<<<pgrid, 256, 0, stream>>>(rowptr, adj, hbuf, t0buf,
                                                   W + (long long)k * W1sz, nullptr, b,
                                                   txw, out, 2.0f, N);
            _Float16* nh = t0buf;
            t0buf = (_Float16*)hbuf;
            hbuf = nh;
        }
    }
}

// Round 14
// 409.359 us; speedup vs baseline: 2.1476x; 1.1819x over previous
//
#include <hip/hip_runtime.h>

#define DD 64
#define NPW 4    // nodes per wave (gather)
#define NPB 16   // nodes per block
#define ASTR 72  // halves per LDS tile row (64 + 8 pad)
#define NBD 128  // histD partial-histogram blocks
#define NBS 64   // histS partial-histogram blocks

typedef _Float16 f16x8 __attribute__((ext_vector_type(8)));
typedef float f32x4 __attribute__((ext_vector_type(4)));
typedef unsigned long long u64;

static __device__ __forceinline__ int rfl(int x) {
    return __builtin_amdgcn_readfirstlane(x);
}

// ---- histD: per-block LDS u8 histogram of dst + per-edge within-block rank ----
__global__ __launch_bounds__(1024) void histD_kernel(
        const int* __restrict__ dst, unsigned char* __restrict__ dstp,
        unsigned char* __restrict__ ranks, int N, int NR, int E, int slice) {
    extern __shared__ unsigned int ldsH[];
    int nw = NR >> 2;
    int t = threadIdx.x;
    for (int i = t; i < nw; i += 1024) ldsH[i] = 0u;
    __syncthreads();
    int base = blockIdx.x * slice;
    int end = min(base + slice, E);
    for (int e = base + t; e < end; e += 1024) {
        int d = __builtin_nontemporal_load(dst + e);
        unsigned int sh = (unsigned int)(d & 3) * 8u;
        unsigned int old = atomicAdd(&ldsH[d >> 2], 1u << sh);
        unsigned char r = (unsigned char)((old >> sh) & 0xFFu);
        __builtin_nontemporal_store(r, ranks + e);
    }
    __syncthreads();
    unsigned int* outp = reinterpret_cast<unsigned int*>(dstp + (size_t)blockIdx.x * NR);
    for (int i = t; i < nw; i += 1024) outp[i] = ldsH[i];
}

// ---- histS: per-block LDS u8 histogram of src ----
__global__ __launch_bounds__(1024) void histS_kernel(
        const int* __restrict__ src, unsigned char* __restrict__ srcp,
        int N, int NR, int E, int slice) {
    extern __shared__ unsigned int ldsH[];
    int nw = NR >> 2;
    int t = threadIdx.x;
    for (int i = t; i < nw; i += 1024) ldsH[i] = 0u;
    __syncthreads();
    int base = blockIdx.x * slice;
    int end = min(base + slice, E);
    for (int e = base + t; e < end; e += 1024) {
        int s = __builtin_nontemporal_load(src + e);
        atomicAdd(&ldsH[s >> 2], 1u << ((unsigned int)(s & 3) * 8u));
    }
    __syncthreads();
    unsigned int* outp = reinterpret_cast<unsigned int*>(srcp + (size_t)blockIdx.x * NR);
    for (int i = t; i < nw; i += 1024) outp[i] = ldsH[i];
}

// ---- scan1: srcp -> dis ; dstp -> per-block exclusive offsets ; node counts scan ----
__global__ __launch_bounds__(1024) void scan1_kernel(
        unsigned char* dstp, const unsigned char* __restrict__ srcp,
        float* __restrict__ dis, int* __restrict__ rowptr,
        int* __restrict__ bsum, int N, int NR) {
    __shared__ int tmp[1024];
    int t = threadIdx.x;
    int g = blockIdx.x * 1024 + t;
    int c = 0;
    if (g < N) {
        int degv = 0;
        #pragma unroll 8
        for (int i = 0; i < NBS; ++i) degv += srcp[(size_t)i * NR + g];
        dis[g] = (degv > 0) ? rsqrtf((float)degv) : 0.0f;
        #pragma unroll 8
        for (int i = 0; i < NBD; ++i) {
            size_t idx = (size_t)i * NR + g;
            int v = dstp[idx];
            dstp[idx] = (unsigned char)c;
            c += v;
        }
    }
    tmp[t] = c;
    __syncthreads();
    for (int off = 1; off < 1024; off <<= 1) {
        int a = (t >= off) ? tmp[t - off] : 0;
        __syncthreads();
        tmp[t] += a;
        __syncthreads();
    }
    if (g < N) rowptr[g] = tmp[t] - c;
    if (t == 1023) bsum[blockIdx.x] = tmp[1023];
}

__global__ __launch_bounds__(128) void scan2_kernel(int* __restrict__ data, int n) {
    __shared__ int tmp[128];
    int t = threadIdx.x;
    int v = (t < n) ? data[t] : 0;
    tmp[t] = v;
    __syncthreads();
    for (int off = 1; off < 128; off <<= 1) {
        int a = (t >= off) ? tmp[t - off] : 0;
        __syncthreads();
        tmp[t] += a;
        __syncthreads();
    }
    if (t < n) data[t] = tmp[t] - v;
}

__global__ void scan3_kernel(int* __restrict__ rowptr, const int* __restrict__ bsum,
                             int N, int E) {
    int g = blockIdx.x * blockDim.x + threadIdx.x;
    if (g < N) rowptr[g] += bsum[g >> 10];
    if (g == 0) rowptr[N] = E;
}

// ---- cvt: P0 = f * x (f = dis>0 ? dis : 1), fp16 ----
__global__ void cvt_kernel(const float* __restrict__ x, const float* __restrict__ dis,
                           _Float16* __restrict__ p0, long long n8) {
    long long i = (long long)blockIdx.x * blockDim.x + threadIdx.x;
    if (i < n8) {
        int node = (int)(i >> 3);
        float dv = dis[node];
        float f = (dv > 0.f) ? dv : 1.0f;
        const float4* x4 = reinterpret_cast<const float4*>(x);
        float4 a = x4[i * 2], b = x4[i * 2 + 1];
        f16x8 h;
        h[0] = (_Float16)(f * a.x); h[1] = (_Float16)(f * a.y);
        h[2] = (_Float16)(f * a.z); h[3] = (_Float16)(f * a.w);
        h[4] = (_Float16)(f * b.x); h[5] = (_Float16)(f * b.y);
        h[6] = (_Float16)(f * b.z); h[7] = (_Float16)(f * b.w);
        reinterpret_cast<f16x8*>(p0)[i] = h;
    }
}

// ---- CSR fill (no atomics, src-only 4B adjacency) ----
__global__ void fill_kernel(const int* __restrict__ src, const int* __restrict__ dst,
                            const int* __restrict__ rowptr,
                            const unsigned char* __restrict__ dstp,
                            const unsigned char* __restrict__ ranks,
                            int* __restrict__ adjS, int E, int slice, int NR) {
    int e = blockIdx.x * blockDim.x + threadIdx.x;
    if (e < E) {
        int s = __builtin_nontemporal_load(src + e);
        int d = __builtin_nontemporal_load(dst + e);
        int i = e / slice;
        int rank = __builtin_nontemporal_load(ranks + e);
        int pos = rowptr[d] + (int)dstp[(size_t)i * NR + d] + rank;
        adjS[pos] = s;   // plain store: reused by 4 gather passes
    }
}

// ---- unweighted gather: acc[8] = sum_e h[src_e][8q..8q+7] (mask for tail) ----
static __device__ __forceinline__ void gather_sum(
        const int* __restrict__ rowptr, const int* __restrict__ adjS,
        const f16x8* __restrict__ h8, int node, int s, int q, float* acc) {
    int beg = rfl(rowptr[node]);
    int end = rfl(rowptr[node + 1]);
    #pragma unroll
    for (int i = 0; i < 8; ++i) acc[i] = 0.f;
    int j = beg + s;
    int e0 = (j < end) ? adjS[j] : 0;
    int e1 = (j + 8 < end) ? adjS[j + 8] : 0;
    float m0 = (j < end) ? 1.f : 0.f;
    float m1 = (j + 8 < end) ? 1.f : 0.f;
    while (j < end) {
        int jn = j + 16;
        int n0 = (jn < end) ? adjS[jn] : 0;
        int n1 = (jn + 8 < end) ? adjS[jn + 8] : 0;
        float nm0 = (jn < end) ? 1.f : 0.f;
        float nm1 = (jn + 8 < end) ? 1.f : 0.f;
        f16x8 g0 = h8[(long long)e0 * 8 + q];
        f16x8 g1 = h8[(long long)e1 * 8 + q];
        #pragma unroll
        for (int i = 0; i < 8; ++i)
            acc[i] += m0 * (float)g0[i] + m1 * (float)g1[i];
        e0 = n0; e1 = n1; m0 = nm0; m1 = nm1; j = jn;
    }
    #pragma unroll
    for (int m = 8; m < 64; m <<= 1) {
        #pragma unroll
        for (int i = 0; i < 8; ++i) acc[i] += __shfl_xor(acc[i], m, 64);
    }
}

// ---- prop_first: P1 = -dis^2 * gather(P0) ; out = b + x@W0 + Tx1@W1 ----
// (x = inv*P0 own row, Tx1 = inv*P1 ; inv = dis>0 ? 1/dis : 1)
__global__ __launch_bounds__(256, 8) void prop_first_kernel(
        const int* __restrict__ rowptr, const int* __restrict__ adjS,
        const float* __restrict__ dis, const _Float16* __restrict__ p0,
        const float* __restrict__ W0, const float* __restrict__ W1,
        const float* __restrict__ bias,
        _Float16* __restrict__ p1out, float* __restrict__ out, int N) {
    __shared__ _Float16 A_lds[NPB][ASTR];   // Tx1
    __shared__ _Float16 X_lds[NPB][ASTR];   // x
    int t = threadIdx.x;
    int nl = t >> 6, lane = t & 63;
    int ct = nl, lr = lane & 15, lk = lane >> 4;

    f16x8 bf1[2], bf0[2];
    #pragma unroll
    for (int kt = 0; kt < 2; ++kt)
        #pragma unroll
        for (int i = 0; i < 8; ++i) {
            int r = kt * 32 + lk * 8 + i;
            bf1[kt][i] = (_Float16)W1[r * DD + ct * 16 + lr];
            bf0[kt][i] = (_Float16)W0[r * DD + ct * 16 + lr];
        }

    int s = lane >> 3, q = lane & 7;
    int node0 = blockIdx.x * NPB + nl * NPW;
    int nv = min(NPW, max(0, N - node0));
    const f16x8* h8 = reinterpret_cast<const f16x8*>(p0);

    for (int ni = 0; ni < nv; ++ni) {
        int node = node0 + ni;
        float acc[8];
        gather_sum(rowptr, adjS, h8, node, s, q, acc);
        if (s == 0) {
            float dv = dis[node];
            float c1 = -dv * dv;
            float invd = (dv > 0.f) ? 1.f / dv : 1.f;
            long long base = (long long)node * DD + q * 8;
            f16x8 p0v = h8[(long long)node * 8 + q];
            f16x8 ph, ah, xh;
            #pragma unroll
            for (int i = 0; i < 8; ++i) {
                float p1 = c1 * acc[i];
                ph[i] = (_Float16)p1;
                ah[i] = (_Float16)(p1 * invd);
                xh[i] = (_Float16)((float)p0v[i] * invd);
            }
            *reinterpret_cast<f16x8*>(p1out + base) = ph;
            int rowi = nl * NPW + ni;
            *reinterpret_cast<f16x8*>(&A_lds[rowi][q * 8]) = ah;
            *reinterpret_cast<f16x8*>(&X_lds[rowi][q * 8]) = xh;
        }
    }
    __syncthreads();

    f32x4 d = {0.f, 0.f, 0.f, 0.f};
    #pragma unroll
    for (int kt = 0; kt < 2; ++kt) {
        f16x8 a = *reinterpret_cast<const f16x8*>(&A_lds[lr][kt * 32 + lk * 8]);
        f16x8 xv = *reinterpret_cast<const f16x8*>(&X_lds[lr][kt * 32 + lk * 8]);
        d = __builtin_amdgcn_mfma_f32_16x16x32_f16(a, bf1[kt], d, 0, 0, 0);
        d = __builtin_amdgcn_mfma_f32_16x16x32_f16(xv, bf0[kt], d, 0, 0, 0);
    }
    int nvb = min(NPB, N - blockIdx.x * NPB);
    int col = ct * 16 + lr;
    float bv = bias[col];
    #pragma unroll
    for (int r = 0; r < 4; ++r) {
        int row = lk * 4 + r;
        if (row < nvb) {
            long long o = (long long)(blockIdx.x * NPB + row) * DD + col;
            out[o] = bv + d[r];
        }
    }
}

// ---- prop_mid: Pout = -2*dis^2*gather(h) - P_old  (all buffers distinct) ----
__global__ __launch_bounds__(256, 8) void prop_mid_kernel(
        const int* __restrict__ rowptr, const int* __restrict__ adjS,
        const float* __restrict__ dis,
        const _Float16* __restrict__ h, const _Float16* __restrict__ t0,
        _Float16* __restrict__ pout, int N) {
    int t = threadIdx.x;
    int nl = t >> 6, lane = t & 63;
    int s = lane >> 3, q = lane & 7;
    int node0 = blockIdx.x * NPB + nl * NPW;
    int nv = min(NPW, max(0, N - node0));
    const f16x8* h8 = reinterpret_cast<const f16x8*>(h);

    for (int ni = 0; ni < nv; ++ni) {
        int node = node0 + ni;
        float acc[8];
        gather_sum(rowptr, adjS, h8, node, s, q, acc);
        if (s == 0) {
            float dv = dis[node];
            float c2 = -2.f * dv * dv;
            long long base = (long long)node * DD + q * 8;
            f16x8 t0v = *reinterpret_cast<const f16x8*>(t0 + base);
            f16x8 vh;
            #pragma unroll
            for (int i = 0; i < 8; ++i)
                vh[i] = (_Float16)(c2 * acc[i] - (float)t0v[i]);
            *reinterpret_cast<f16x8*>(pout + base) = vh;
        }
    }
}

// ---- gemm3: out += (inv*P2)@W2 + (inv*P3)@W3 + (inv*P4)@W4 (streaming) ----
__global__ __launch_bounds__(256, 8) void gemm3_kernel(
        const _Float16* __restrict__ P2, const _Float16* __restrict__ P3,
        const _Float16* __restrict__ P4, const float* __restrict__ dis,
        const float* __restrict__ W2, const float* __restrict__ W3,
        const float* __restrict__ W4, float* __restrict__ out, int N) {
    __shared__ _Float16 T[3][NPB][ASTR];
    int t = threadIdx.x;
    int nl = t >> 6, lane = t & 63;
    int ct = nl, lr = lane & 15, lk = lane >> 4;

    f16x8 bf[3][2];
    #pragma unroll
    for (int kt = 0; kt < 2; ++kt)
        #pragma unroll
        for (int i = 0; i < 8; ++i) {
            int r = kt * 32 + lk * 8 + i;
            bf[0][kt][i] = (_Float16)W2[r * DD + ct * 16 + lr];
            bf[1][kt][i] = (_Float16)W3[r * DD + ct * 16 + lr];
            bf[2][kt][i] = (_Float16)W4[r * DD + ct * 16 + lr];
        }

    int nb0 = blockIdx.x * NPB;
    int nvb = min(NPB, N - nb0);
    for (int idx = t; idx < 384; idx += 256) {
        int tile = idx >> 7;
        int rem = idx & 127;
        int row = rem >> 3, q = rem & 7;
        if (row < nvb) {
            int node = nb0 + row;
            float dv = dis[node];
            float invd = (dv > 0.f) ? 1.f / dv : 1.f;
            const _Float16* srcb = (tile == 0) ? P2 : (tile == 1) ? P3 : P4;
            f16x8 p = *reinterpret_cast<const f16x8*>(srcb + (long long)node * DD + q * 8);
            f16x8 vh;
            #pragma unroll
            for (int i = 0; i < 8; ++i) vh[i] = (_Float16)((float)p[i] * invd);
            *reinterpret_cast<f16x8*>(&T[tile][row][q * 8]) = vh;
        }
    }
    __syncthreads();

    f32x4 d = {0.f, 0.f, 0.f, 0.f};
    #pragma unroll
    for (int kt = 0; kt < 2; ++kt)
        #pragma unroll
        for (int tile = 0; tile < 3; ++tile) {
            f16x8 a = *reinterpret_cast<const f16x8*>(&T[tile][lr][kt * 32 + lk * 8]);
            d = __builtin_amdgcn_mfma_f32_16x16x32_f16(a, bf[tile][kt], d, 0, 0, 0);
        }
    int col = ct * 16 + lr;
    #pragma unroll
    for (int r = 0; r < 4; ++r) {
        int row = lk * 4 + r;
        if (row < nvb) {
            long long o = (long long)(nb0 + row) * DD + col;
            out[o] = out[o] + d[r];
        }
    }
}

// ---- gemm1 (generic-K fallback): out += (inv*P)@Wk ----
__global__ __launch_bounds__(256, 8) void gemm1_kernel(
        const _Float16* __restrict__ P, const float* __restrict__ dis,
        const float* __restrict__ Wk, float* __restrict__ out, int N) {
    __shared__ _Float16 T[NPB][ASTR];
    int t = threadIdx.x;
    int nl = t >> 6, lane = t & 63;
    int ct = nl, lr = lane & 15, lk = lane >> 4;
    f16x8 bf[2];
    #pragma unroll
    for (int kt = 0; kt < 2; ++kt)
        #pragma unroll
        for (int i = 0; i < 8; ++i) {
            int r = kt * 32 + lk * 8 + i;
            bf[kt][i] = (_Float16)Wk[r * DD + ct * 16 + lr];
        }
    int nb0 = blockIdx.x * NPB;
    int nvb = min(NPB, N - nb0);
    for (int idx = t; idx < 128; idx += 256) {
        int row = idx >> 3, q = idx & 7;
        if (row < nvb) {
            int node = nb0 + row;
            float dv = dis[node];
            float invd = (dv > 0.f) ? 1.f / dv : 1.f;
            f16x8 p = *reinterpret_cast<const f16x8*>(P + (long long)node * DD + q * 8);
            f16x8 vh;
            #pragma unroll
            for (int i = 0; i < 8; ++i) vh[i] = (_Float16)((float)p[i] * invd);
            *reinterpret_cast<f16x8*>(&T[row][q * 8]) = vh;
        }
    }
    __syncthreads();
    f32x4 d = {0.f, 0.f, 0.f, 0.f};
    #pragma unroll
    for (int kt = 0; kt < 2; ++kt) {
        f16x8 a = *reinterpret_cast<const f16x8*>(&T[lr][kt * 32 + lk * 8]);
        d = __builtin_amdgcn_mfma_f32_16x16x32_f16(a, bf[kt], d, 0, 0, 0);
    }
    int col = ct * 16 + lr;
    #pragma unroll
    for (int r = 0; r < 4; ++r) {
        int row = lk * 4 + r;
        if (row < nvb) {
            long long o = (long long)(nb0 + row) * DD + col;
            out[o] = out[o] + d[r];
        }
    }
}

extern "C" void kernel_launch(void* const* d_in, const int* in_sizes, int n_in,
                              void* d_out, int out_size, void* d_ws, size_t ws_size,
                              hipStream_t stream) {
    const float* x  = (const float*)d_in[0];
    const int*   ei = (const int*)d_in[1];
    const float* W  = (const float*)d_in[2];
    const float* b  = (const float*)d_in[3];
    float* out = (float*)d_out;

    const int N = in_sizes[0] / DD;
    const int E = in_sizes[1] / 2;
    const int K = in_sizes[2] / (DD * DD);
    const long long ND = (long long)N * DD;
    const int NR = ((N + 3) / 4) * 4;

    const int* src = ei;
    const int* dst = ei + E;

    size_t off = 0;
    char* base = (char*)d_ws;
    auto alloc = [&](size_t bytes) {
        char* p = base + off;
        off = (off + bytes + 63) & ~(size_t)63;
        return p;
    };
    float* dis = (float*)alloc((size_t)N * 4);
    int* rowptr = (int*)alloc((size_t)(N + 1) * 4);
    int* bsum = (int*)alloc(512);
    char* dstp_base = alloc((size_t)NBD * NR);       // dead after fill -> bufC overlay
    unsigned char* dstp = (unsigned char*)dstp_base;
    unsigned char* srcp = (unsigned char*)alloc((size_t)NBS * NR);
    unsigned char* ranks = (unsigned char*)alloc((size_t)E);
    int* adjS = (int*)alloc((size_t)E * 4);
    _Float16* bufA = (_Float16*)alloc((size_t)ND * 2);   // P0 -> ...
    _Float16* bufB = (_Float16*)alloc((size_t)ND * 2);   // P1 -> ...
    _Float16* bufC = (_Float16*)dstp_base;               // overlays dstp(+srcp), 12.8MB

    const int sliceD = (E + NBD - 1) / NBD;
    const int sliceS = (E + NBS - 1) / NBS;
    const size_t ldsH = (size_t)NR;

    histD_kernel<<<NBD, 1024, ldsH, stream>>>(dst, dstp, ranks, N, NR, E, sliceD);
    histS_kernel<<<NBS, 1024, ldsH, stream>>>(src, srcp, N, NR, E, sliceS);

    const int nb = (N + 1023) / 1024;
    scan1_kernel<<<nb, 1024, 0, stream>>>(dstp, srcp, dis, rowptr, bsum, N, NR);
    scan2_kernel<<<1, 128, 0, stream>>>(bsum, nb);
    scan3_kernel<<<(N + 255) / 256, 256, 0, stream>>>(rowptr, bsum, N, E);

    const long long n8 = ND / 8;
    cvt_kernel<<<(int)((n8 + 255) / 256), 256, 0, stream>>>(x, dis, bufA, n8);

    fill_kernel<<<(E + 255) / 256, 256, 0, stream>>>(src, dst, rowptr, dstp,
                                                     ranks, adjS, E, sliceD, NR);

    const int pgrid = (N + NPB - 1) / NPB;
    const int Wsz = DD * DD;

    // P1 = -dis^2 * gather(P0) ; out = b + x@W0 + Tx1@W1
    prop_first_kernel<<<pgrid, 256, 0, stream>>>(rowptr, adjS, dis, bufA,
                                                 W, W + Wsz, b, bufB, out, N);

    if (K == 5) {
        // P2 = -2 dis^2 gather(P1) - P0   -> bufC  (dstp dead after fill)
        prop_mid_kernel<<<pgrid, 256, 0, stream>>>(rowptr, adjS, dis, bufB, bufA, bufC, N);
        // P3 = -2 dis^2 gather(P2) - P1   -> bufA  (P0 dead)
        prop_mid_kernel<<<pgrid, 256, 0, stream>>>(rowptr, adjS, dis, bufC, bufB, bufA, N);
        // P4 = -2 dis^2 gather(P3) - P2   -> bufB  (P1 dead)
        prop_mid_kernel<<<pgrid, 256, 0, stream>>>(rowptr, adjS, dis, bufA, bufC, bufB, N);
        // out += Tx2@W2 + Tx3@W3 + Tx4@W4   (Tx_k = inv*P_k)
        gemm3_kernel<<<pgrid, 256, 0, stream>>>(bufC, bufA, bufB, dis,
                                                W + 2 * Wsz, W + 3 * Wsz, W + 4 * Wsz,
                                                out, N);
    } else {
        // generic: 3-buffer rotation, per-k streaming GEMM
        _Float16* t0 = bufA;   // P_{k-2}
        _Float16* h  = bufB;   // P_{k-1}
        _Float16* fr = bufC;   // free
        for (int k = 2; k < K; ++k) {
            prop_mid_kernel<<<pgrid, 256, 0, stream>>>(rowptr, adjS, dis, h, t0, fr, N);
            gemm1_kernel<<<pgrid, 256, 0, stream>>>(fr, dis, W + (long long)k * Wsz,
                                                    out, N);
            _Float16* nfree = t0;
            t0 = h; h = fr; fr = nfree;
        }
    }
}